// Round 2
// baseline (1183.834 us; speedup 1.0000x reference)
//
#include <hip/hip_runtime.h>

typedef unsigned short u16;
typedef unsigned int u32;
typedef __attribute__((ext_vector_type(8))) short short8;
typedef __attribute__((ext_vector_type(4))) float f32x4;
typedef __attribute__((ext_vector_type(4))) u16 u16x4;

#define N_NODES 16384
#define B_MOL   256
#define NPM     64
#define E_EDGES 65536
#define FMAXF   32
#define AMAXA   16
#define HID     960
#define HID4    240
#define NFG     205
#define BF_ROWS 8192
#define OUT1    7864320   // B*FMAX*HID

__device__ __forceinline__ float bf2f(u16 u){ u32 x=((u32)u)<<16; float f; __builtin_memcpy(&f,&x,4); return f; }
__device__ __forceinline__ u16 f2bf(float f){ u32 x; __builtin_memcpy(&x,&f,4); x += 0x7FFFu + ((x>>16)&1u); return (u16)(x>>16); }

// ---------- dtype detection: fp32 inputs read as u16 have garbage-exponent even halves ----------
__global__ __launch_bounds__(256) void k_detect(const u16* __restrict__ gx, int* __restrict__ flag){
    __shared__ int cnt;
    if (threadIdx.x==0) cnt = 0;
    __syncthreads();
    u16 v = gx[threadIdx.x*2];          // low half of fp32 mantissa, or a clean bf16 value
    int e = (v>>7) & 0xFF;
    if (e >= 0xC0) atomicAdd(&cnt, 1);  // |v| >= 2^65 as bf16 -> impossible for N(0,1) bf16 data
    __syncthreads();
    if (threadIdx.x==0) *flag = (cnt > 16) ? 1 : 0;   // 1 => inputs are fp32
}
// normalize any float tensor to bf16
__global__ __launch_bounds__(256) void k_norm(const void* __restrict__ src, u16* __restrict__ dst,
                                              int n, const int* __restrict__ flag){
    int i = blockIdx.x*256 + threadIdx.x;
    if (i >= n) return;
    if (*flag) dst[i] = f2bf(((const float*)src)[i]);
    else       dst[i] = ((const u16*)src)[i];
}

// ---------------- small utility kernels ----------------
__global__ __launch_bounds__(256) void k_zero(int* p, int n){
    int i = blockIdx.x*256 + threadIdx.x; if (i < n) p[i] = 0;
}
__global__ __launch_bounds__(256) void k_hist(const int* __restrict__ dst, int* __restrict__ deg){
    int e = blockIdx.x*256 + threadIdx.x; if (e < E_EDGES) atomicAdd(&deg[dst[e]], 1);
}
__global__ __launch_bounds__(256) void k_dinv(const int* __restrict__ deg, float* __restrict__ dinv){
    int n = blockIdx.x*256 + threadIdx.x; if (n < N_NODES) dinv[n] = rsqrtf(1.0f + (float)deg[n]);
}
__global__ __launch_bounds__(256) void k_scan(const int* __restrict__ deg, int* __restrict__ off, int* __restrict__ cur){
    __shared__ int ps[256];
    int t = threadIdx.x;
    const int chunk = N_NODES/256; // 64
    int base0 = t*chunk;
    int s = 0;
    for (int i=0;i<chunk;i++) s += deg[base0+i];
    ps[t] = s; __syncthreads();
    for (int ofs=1; ofs<256; ofs<<=1){
        int v = ps[t];
        int add = (t>=ofs) ? ps[t-ofs] : 0;
        __syncthreads();
        ps[t] = v + add;
        __syncthreads();
    }
    int run = (t==0) ? 0 : ps[t-1];
    for (int i=0;i<chunk;i++){ off[base0+i]=run; cur[base0+i]=run; run += deg[base0+i]; }
    if (t==255) off[N_NODES] = run;
}
__global__ __launch_bounds__(256) void k_scatter(const int* __restrict__ src, const int* __restrict__ dst,
                                                 const float* __restrict__ dinv, int* __restrict__ cur,
                                                 int* __restrict__ csr_s, float* __restrict__ csr_w){
    int e = blockIdx.x*256 + threadIdx.x;
    if (e < E_EDGES){
        int s = src[e], d = dst[e];
        int p = atomicAdd(&cur[d], 1);
        csr_s[p] = s;
        csr_w[p] = dinv[s]*dinv[d];
    }
}
__global__ __launch_bounds__(256) void k_aggx(const u16* __restrict__ x, const float* __restrict__ dinv,
                                              const int* __restrict__ off, const int* __restrict__ csr_s,
                                              const float* __restrict__ csr_w, float* __restrict__ aggx){
    int n = blockIdx.x*256 + threadIdx.x;
    if (n >= N_NODES) return;
    float di = dinv[n], sw = di*di;
    float a[5];
    #pragma unroll
    for (int k=0;k<5;k++) a[k] = sw * bf2f(x[n*5+k]);
    int j0 = off[n], j1 = off[n+1];
    for (int j=j0;j<j1;j++){
        int s = csr_s[j]; float w = csr_w[j];
        #pragma unroll
        for (int k=0;k<5;k++) a[k] += w * bf2f(x[s*5+k]);
    }
    #pragma unroll
    for (int k=0;k<5;k++) aggx[n*5+k] = a[k];
}
__global__ __launch_bounds__(256) void k_h1(const float* __restrict__ aggx, const u16* __restrict__ W1,
                                            const u16* __restrict__ b1, u16* __restrict__ h1b){
    int id = blockIdx.x*256 + threadIdx.x;      // N*240 exact
    int n = id / HID4; int c4 = (id - n*HID4)*4;
    float a[5];
    #pragma unroll
    for (int k=0;k<5;k++) a[k] = aggx[n*5+k];
    float r0=bf2f(b1[c4+0]), r1=bf2f(b1[c4+1]), r2=bf2f(b1[c4+2]), r3=bf2f(b1[c4+3]);
    #pragma unroll
    for (int k=0;k<5;k++){
        u16x4 wv = *(const u16x4*)(W1 + k*HID + c4);
        r0 += a[k]*bf2f(wv.x); r1 += a[k]*bf2f(wv.y); r2 += a[k]*bf2f(wv.z); r3 += a[k]*bf2f(wv.w);
    }
    r0 = fmaxf(r0,0.f); r1 = fmaxf(r1,0.f); r2 = fmaxf(r2,0.f); r3 = fmaxf(r3,0.f);
    u16x4 o; o.x=f2bf(r0); o.y=f2bf(r1); o.z=f2bf(r2); o.w=f2bf(r3);
    *(u16x4*)(h1b + (size_t)n*HID + c4) = o;
}
__global__ __launch_bounds__(256) void k_p1(const u16* __restrict__ h1b, const float* __restrict__ dinv,
                                            const int* __restrict__ off, const int* __restrict__ csr_s,
                                            const float* __restrict__ csr_w, u16* __restrict__ P1b){
    int id = blockIdx.x*256 + threadIdx.x;      // N*240 exact
    int n = id / HID4; int c4 = (id - n*HID4)*4;
    float di = dinv[n], sw = di*di;
    u16x4 h = *(const u16x4*)(h1b + (size_t)n*HID + c4);
    float s0=sw*bf2f(h.x), s1=sw*bf2f(h.y), s2=sw*bf2f(h.z), s3=sw*bf2f(h.w);
    int j0 = off[n], j1 = off[n+1];
    for (int j=j0;j<j1;j++){
        int s = csr_s[j]; float w = csr_w[j];
        u16x4 v = *(const u16x4*)(h1b + (size_t)s*HID + c4);
        s0 += w*bf2f(v.x); s1 += w*bf2f(v.y); s2 += w*bf2f(v.z); s3 += w*bf2f(v.w);
    }
    u16x4 o; o.x=f2bf(s0); o.y=f2bf(s1); o.z=f2bf(s2); o.w=f2bf(s3);
    *(u16x4*)(P1b + (size_t)n*HID + c4) = o;
}
__global__ __launch_bounds__(256) void k_gm(const u16* __restrict__ P1b, u16* __restrict__ gmb){
    int id = blockIdx.x*256 + threadIdx.x;      // 256*240 exact
    int b = id / HID4; int c4 = (id - b*HID4)*4;
    float s0=0,s1=0,s2=0,s3=0;
    for (int i=0;i<NPM;i++){
        u16x4 v = *(const u16x4*)(P1b + (size_t)(b*NPM+i)*HID + c4);
        s0 += bf2f(v.x); s1 += bf2f(v.y); s2 += bf2f(v.z); s3 += bf2f(v.w);
    }
    const float inv = 1.0f/(float)NPM;
    u16x4 o; o.x=f2bf(s0*inv); o.y=f2bf(s1*inv); o.z=f2bf(s2*inv); o.w=f2bf(s3*inv);
    *(u16x4*)(gmb + (size_t)b*HID + c4) = o;
}
__global__ __launch_bounds__(256) void k_pr(const u16* __restrict__ P1b, const int* __restrict__ fgi,
                                            const int* __restrict__ ptr, u16* __restrict__ prb,
                                            float* __restrict__ evec, u16* __restrict__ maskb,
                                            float* __restrict__ maskf, const int* __restrict__ flag){
    int id = blockIdx.x*256 + threadIdx.x;      // 8192*240 exact
    int bf = id / HID4; int c4 = (id - bf*HID4)*4;
    int b = bf >> 5;
    int base = ptr[b];
    float s0=0,s1=0,s2=0,s3=0; int cnt=0;
    #pragma unroll
    for (int a=0;a<AMAXA;a++){
        int idx = fgi[bf*AMAXA + a];
        if (idx >= 0){
            cnt++;
            u16x4 v = *(const u16x4*)(P1b + (size_t)(base+idx)*HID + c4);
            s0 += bf2f(v.x); s1 += bf2f(v.y); s2 += bf2f(v.z); s3 += bf2f(v.w);
        }
    }
    float inv = (cnt>0) ? 1.0f/(float)cnt : 0.0f;
    u16x4 o; o.x=f2bf(s0*inv); o.y=f2bf(s1*inv); o.z=f2bf(s2*inv); o.w=f2bf(s3*inv);
    *(u16x4*)(prb + (size_t)bf*HID + c4) = o;
    if (c4 == 0){
        float e = (cnt>0) ? 1.0f : 0.0f;
        evec[bf] = e;
        if (*flag) maskf[bf] = e;
        else       maskb[bf] = f2bf(e);
    }
}
__global__ __launch_bounds__(256) void k_transpose(const u16* __restrict__ src, u16* __restrict__ dst, int R, int C){
    __shared__ __attribute__((aligned(16))) u16 t[32][33];
    int c0 = blockIdx.x*32, r0 = blockIdx.y*32;
    int tx = threadIdx.x, ty = threadIdx.y;   // 32 x 8
    #pragma unroll
    for (int i=0;i<4;i++) t[ty+i*8][tx] = src[(size_t)(r0+ty+i*8)*C + c0+tx];
    __syncthreads();
    #pragma unroll
    for (int i=0;i<4;i++) dst[(size_t)(c0+ty+i*8)*R + r0+tx] = t[tx][ty+i*8];
}
__global__ __launch_bounds__(256) void k_cast(const u16* __restrict__ in, float* __restrict__ out, int n){
    int i = blockIdx.x*256 + threadIdx.x; if (i<n) out[i] = bf2f(in[i]);
}
__global__ __launch_bounds__(256) void k_rowvec(const float* __restrict__ v, const u16* __restrict__ M,
                                                int ld, int K, float* __restrict__ out){
    int c = blockIdx.x*256 + threadIdx.x;
    if (c < HID){
        float s = 0.f;
        for (int k=0;k<K;k++) s += v[k]*bf2f(M[(size_t)k*ld + c]);
        out[c] = s;
    }
}
__global__ __launch_bounds__(256) void k_addc(const float* __restrict__ a, const float* __restrict__ b,
                                              const u16* __restrict__ fb, float* __restrict__ out){
    int c = blockIdx.x*256 + threadIdx.x; if (c<HID) out[c] = a[c] + b[c] + bf2f(fb[c]);
}

// ---------------- bf16 MFMA GEMM: C[M,960] = A[M,K] @ Bt[960,K]^T ----------------
template<int FINAL>
__global__ __launch_bounds__(256) void k_gemm(
    const u16* __restrict__ A, int lda,
    const u16* __restrict__ Bt, int ldb,
    float* __restrict__ Cf, u16* __restrict__ Cb, int cbf16,
    int M, int K,
    const int* __restrict__ fg_type, const float* __restrict__ evec,
    const float* __restrict__ fgA, const float* __restrict__ pWbM,
    const float* __restrict__ vb, const float* __restrict__ c0,
    const float* __restrict__ Gc, const int* __restrict__ flag)
{
    __shared__ __attribute__((aligned(16))) u16 As[64*40];
    __shared__ __attribute__((aligned(16))) u16 Bs[64*40];
    const int tid = threadIdx.x;
    const int wave = tid>>6, lane = tid&63;
    const int wm = wave>>1, wn = wave&1;
    const int q = lane>>4, l16 = lane&15;
    const int m0 = blockIdx.x*64, n0 = blockIdx.y*64;
    const int sm = tid>>2, sk = (tid&3)*8;

    f32x4 acc00={0,0,0,0}, acc01={0,0,0,0}, acc10={0,0,0,0}, acc11={0,0,0,0};
    const bool aOk = (m0+sm) < M;
    const u16* Ap = A + (size_t)(m0+sm)*lda + sk;
    const u16* Bp = Bt + (size_t)(n0+sm)*ldb + sk;

    for (int k0=0; k0<K; k0+=32){
        short8 av = {0,0,0,0,0,0,0,0};
        if (aOk) av = *(const short8*)(Ap + k0);
        short8 bv = *(const short8*)(Bp + k0);
        *(short8*)(As + sm*40 + sk) = av;
        *(short8*)(Bs + sm*40 + sk) = bv;
        __syncthreads();
        short8 a0 = *(const short8*)(As + (wm*32      + l16)*40 + q*8);
        short8 a1 = *(const short8*)(As + (wm*32 + 16 + l16)*40 + q*8);
        short8 b0 = *(const short8*)(Bs + (wn*32      + l16)*40 + q*8);
        short8 b1 = *(const short8*)(Bs + (wn*32 + 16 + l16)*40 + q*8);
        acc00 = __builtin_amdgcn_mfma_f32_16x16x32_bf16(a0,b0,acc00,0,0,0);
        acc01 = __builtin_amdgcn_mfma_f32_16x16x32_bf16(a0,b1,acc01,0,0,0);
        acc10 = __builtin_amdgcn_mfma_f32_16x16x32_bf16(a1,b0,acc10,0,0,0);
        acc11 = __builtin_amdgcn_mfma_f32_16x16x32_bf16(a1,b1,acc11,0,0,0);
        __syncthreads();
    }

    int isf = FINAL ? *flag : 0;
    #pragma unroll
    for (int i=0;i<2;i++){
        int rowb = m0 + wm*32 + i*16 + q*4;
        #pragma unroll
        for (int j=0;j<2;j++){
            int col = n0 + wn*32 + j*16 + l16;
            f32x4 av = (i==0) ? ((j==0)?acc00:acc01) : ((j==0)?acc10:acc11);
            #pragma unroll
            for (int r=0;r<4;r++){
                int row = rowb + r;
                if (row >= M) continue;
                float v = av[r];
                if (FINAL){
                    int bb = row>>5, ff = row&31;
                    int ty = fg_type[row];
                    float e = evec[row];
                    v += fgA[ty*HID+col] + pWbM[ff*HID+col] + e*vb[col] + c0[col] + Gc[bb*HID+col];
                    if (isf) Cf[(size_t)row*HID + col] = v;
                    else     Cb[(size_t)row*HID + col] = f2bf(v);
                } else if (cbf16){
                    Cb[(size_t)row*HID + col] = f2bf(v);
                } else {
                    Cf[(size_t)row*HID + col] = v;
                }
            }
        }
    }
}

extern "C" void kernel_launch(void* const* d_in, const int* in_sizes, int n_in,
                              void* d_out, int out_size, void* d_ws, size_t ws_size,
                              hipStream_t stream) {
    const int* edge_idx  = (const int*)d_in[1];
    const int* ptr       = (const int*)d_in[3];
    const int* fg_type   = (const int*)d_in[4];
    const int* fg_idx    = (const int*)d_in[5];

    // ---- workspace layout (aliased lifetimes) ----
    char* w = (char*)d_ws;
    auto nxt = [&](size_t b)->char*{ char* p = w; w += (b + 255) & ~(size_t)255; return p; };
    // big region 0: fuseWT+Ub (early) -> h1b (mid) -> prb (late)
    u16* big0   = (u16*)nxt((size_t)N_NODES*HID*2);       // 31.46 MB
    u16* fuseWT = big0;                                   // [960,2560]
    u16* Ub     = big0 + (size_t)HID*2560;                // [960,960]
    u16* h1b    = big0;                                   // [16384,960]
    u16* prb    = big0;                                   // [8192,960]
    u16* P1b    = (u16*)nxt((size_t)N_NODES*HID*2);       // 31.46 MB
    // persistent
    u16*  WbigT  = (u16*) nxt((size_t)HID*HID*2);
    u16*  WglobT = (u16*) nxt((size_t)HID*HID*2);
    float* fgA   = (float*)nxt((size_t)NFG*HID*4);
    float* pWbM  = (float*)nxt((size_t)FMAXF*HID*4);
    float* b2f   = (float*)nxt(HID*4);
    float* projbf= (float*)nxt(HID*4);
    float* tvb   = (float*)nxt(HID*4);
    float* vb    = (float*)nxt(HID*4);
    float* cC    = (float*)nxt(HID*4);
    float* gvec  = (float*)nxt(HID*4);
    float* c0    = (float*)nxt(HID*4);
    int*   deg   = (int*)  nxt(N_NODES*4);
    float* dinv  = (float*)nxt(N_NODES*4);
    int*   off   = (int*)  nxt((N_NODES+1)*4);
    int*   cur   = (int*)  nxt(N_NODES*4);
    int*   csr_s = (int*)  nxt(E_EDGES*4);
    float* csr_w = (float*)nxt(E_EDGES*4);
    float* aggx  = (float*)nxt((size_t)N_NODES*5*4);
    float* evec  = (float*)nxt(BF_ROWS*4);
    u16*   gmb   = (u16*)  nxt((size_t)B_MOL*HID*2);
    float* Gc    = (float*)nxt((size_t)B_MOL*HID*4);
    int*   flag  = (int*)  nxt(256);
    // normalized bf16 copies of all float inputs
    u16* gxn    = (u16*)nxt((size_t)N_NODES*5*2);
    u16* W1n    = (u16*)nxt((size_t)5*HID*2);
    u16* b1n    = (u16*)nxt((size_t)HID*2);
    u16* W2n    = (u16*)nxt((size_t)HID*HID*2);
    u16* b2n    = (u16*)nxt((size_t)HID*2);
    u16* fgeN   = (u16*)nxt((size_t)NFG*512*2);
    u16* posN   = (u16*)nxt((size_t)160*128*2);
    u16* projWn = (u16*)nxt((size_t)HID*HID*2);
    u16* projbn = (u16*)nxt((size_t)HID*2);
    u16* fuseWn = (u16*)nxt((size_t)2560*HID*2);
    u16* fusebn = (u16*)nxt((size_t)HID*2);

    // ---- dtype detect + normalize ----
    k_detect<<<1,256,0,stream>>>((const u16*)d_in[0], flag);
    auto norm = [&](const void* s, u16* d, int n){ k_norm<<<(n+255)/256,256,0,stream>>>(s, d, n, flag); };
    norm(d_in[0],  gxn,    N_NODES*5);
    norm(d_in[6],  W1n,    5*HID);
    norm(d_in[7],  b1n,    HID);
    norm(d_in[8],  W2n,    HID*HID);
    norm(d_in[9],  b2n,    HID);
    norm(d_in[10], fgeN,   NFG*512);
    norm(d_in[11], posN,   160*128);
    norm(d_in[12], projWn, HID*HID);
    norm(d_in[13], projbn, HID);
    norm(d_in[14], fuseWn, 2560*HID);
    norm(d_in[15], fusebn, HID);

    const int* fl = flag;
    #define GEMM_TAIL nullptr,nullptr,nullptr,nullptr,nullptr,nullptr,nullptr,fl

    // ---- weight precompute path ----
    k_transpose<<<dim3(HID/32, 2560/32), dim3(32,8), 0, stream>>>(fuseWn, fuseWT, 2560, HID);
    k_gemm<0><<<dim3(15,15),256,0,stream>>>(fuseWT+640, 2560, projWn, HID, nullptr, Ub, 1, HID, HID, GEMM_TAIL);
    k_gemm<0><<<dim3(15,15),256,0,stream>>>(Ub, HID, W2n, HID, nullptr, WbigT, 1, HID, HID, GEMM_TAIL);
    k_gemm<0><<<dim3(15,15),256,0,stream>>>(fuseWT+1600, 2560, W2n, HID, nullptr, WglobT, 1, HID, HID, GEMM_TAIL);
    k_gemm<0><<<dim3(4,15),256,0,stream>>>(fgeN, 512, fuseWT, 2560, fgA, nullptr, 0, NFG, 512, GEMM_TAIL);
    k_gemm<0><<<dim3(1,15),256,0,stream>>>(posN, 128, fuseWT+512, 2560, pWbM, nullptr, 0, FMAXF, 128, GEMM_TAIL);
    // bias vectors
    k_cast<<<4,256,0,stream>>>(b2n, b2f, HID);
    k_cast<<<4,256,0,stream>>>(projbn, projbf, HID);
    k_rowvec<<<4,256,0,stream>>>(b2f,   projWn,            HID, HID, tvb);
    k_rowvec<<<4,256,0,stream>>>(tvb,   fuseWn + 640*HID,  HID, HID, vb);
    k_rowvec<<<4,256,0,stream>>>(projbf,fuseWn + 640*HID,  HID, HID, cC);
    k_rowvec<<<4,256,0,stream>>>(b2f,   fuseWn + 1600*HID, HID, HID, gvec);
    k_addc<<<4,256,0,stream>>>(cC, gvec, fusebn, c0);

    // ---- graph path ----
    k_zero<<<64,256,0,stream>>>(deg, N_NODES);
    k_hist<<<256,256,0,stream>>>(edge_idx + E_EDGES, deg);
    k_dinv<<<64,256,0,stream>>>(deg, dinv);
    k_scan<<<1,256,0,stream>>>(deg, off, cur);
    k_scatter<<<256,256,0,stream>>>(edge_idx, edge_idx + E_EDGES, dinv, cur, csr_s, csr_w);
    k_aggx<<<64,256,0,stream>>>(gxn, dinv, off, csr_s, csr_w, aggx);
    k_h1<<<15360,256,0,stream>>>(aggx, W1n, b1n, h1b);          // overwrites fuseWT/Ub (dead)
    k_p1<<<15360,256,0,stream>>>(h1b, dinv, off, csr_s, csr_w, P1b);
    k_gm<<<240,256,0,stream>>>(P1b, gmb);
    k_pr<<<7680,256,0,stream>>>(P1b, fg_idx, ptr, prb,          // overwrites h1b (dead)
                                evec, (u16*)d_out + OUT1, (float*)d_out + OUT1, flag);

    // Gc = gm @ (W2 Wd)
    k_gemm<0><<<dim3(4,15),256,0,stream>>>(gmb, HID, WglobT, HID, Gc, nullptr, 0, B_MOL, HID, GEMM_TAIL);
    // out = pr @ (W2 projW Wc) + epilogue
    k_gemm<1><<<dim3(128,15),256,0,stream>>>(prb, HID, WbigT, HID, (float*)d_out, (u16*)d_out, 0, BF_ROWS, HID,
                                             fg_type, evec, fgA, pWbM, vb, c0, Gc, flag);
    (void)in_sizes; (void)n_in; (void)out_size; (void)ws_size;
}

// Round 3
// 390.061 us; speedup vs baseline: 3.0350x; 3.0350x over previous
//
#include <hip/hip_runtime.h>

typedef unsigned short u16;
typedef unsigned int u32;
typedef __attribute__((ext_vector_type(8))) short short8;
typedef __attribute__((ext_vector_type(4))) float f32x4;
typedef __attribute__((ext_vector_type(4))) u16 u16x4;

#define N_NODES 16384
#define B_MOL   256
#define NPM     64
#define E_EDGES 65536
#define FMAXF   32
#define AMAXA   16
#define HID     960
#define HID4    240
#define NFG     205
#define BF_ROWS 8192
#define OUT1    7864320   // B*FMAX*HID

__device__ __forceinline__ float bf2f(u16 u){ u32 x=((u32)u)<<16; float f; __builtin_memcpy(&f,&x,4); return f; }
__device__ __forceinline__ u16 f2bf(float f){ u32 x; __builtin_memcpy(&x,&f,4); x += 0x7FFFu + ((x>>16)&1u); return (u16)(x>>16); }

// ---------- dtype detection: fp32 inputs read as u16 have garbage-exponent even halves ----------
__global__ __launch_bounds__(256) void k_detect(const u16* __restrict__ gx, int* __restrict__ flag){
    __shared__ int cnt;
    if (threadIdx.x==0) cnt = 0;
    __syncthreads();
    u16 v = gx[threadIdx.x*2];          // low half of fp32 mantissa, or a clean bf16 value
    int e = (v>>7) & 0xFF;
    if (e >= 0xC0) atomicAdd(&cnt, 1);  // |v| >= 2^65 as bf16 -> impossible for N(0,1) bf16 data
    __syncthreads();
    if (threadIdx.x==0) *flag = (cnt > 16) ? 1 : 0;   // 1 => inputs are fp32
}
// normalize any float tensor to bf16
__global__ __launch_bounds__(256) void k_norm(const void* __restrict__ src, u16* __restrict__ dst,
                                              int n, const int* __restrict__ flag){
    int i = blockIdx.x*256 + threadIdx.x;
    if (i >= n) return;
    if (*flag) dst[i] = f2bf(((const float*)src)[i]);
    else       dst[i] = ((const u16*)src)[i];
}

// ---------------- small utility kernels ----------------
__global__ __launch_bounds__(256) void k_zero(int* p, int n){
    int i = blockIdx.x*256 + threadIdx.x; if (i < n) p[i] = 0;
}
__global__ __launch_bounds__(256) void k_hist(const int* __restrict__ dst, int* __restrict__ deg){
    int e = blockIdx.x*256 + threadIdx.x; if (e < E_EDGES) atomicAdd(&deg[dst[e]], 1);
}
__global__ __launch_bounds__(256) void k_dinv(const int* __restrict__ deg, float* __restrict__ dinv){
    int n = blockIdx.x*256 + threadIdx.x; if (n < N_NODES) dinv[n] = rsqrtf(1.0f + (float)deg[n]);
}
__global__ __launch_bounds__(256) void k_scan(const int* __restrict__ deg, int* __restrict__ off, int* __restrict__ cur){
    __shared__ int ps[256];
    int t = threadIdx.x;
    const int chunk = N_NODES/256; // 64
    int base0 = t*chunk;
    int s = 0;
    for (int i=0;i<chunk;i++) s += deg[base0+i];
    ps[t] = s; __syncthreads();
    for (int ofs=1; ofs<256; ofs<<=1){
        int v = ps[t];
        int add = (t>=ofs) ? ps[t-ofs] : 0;
        __syncthreads();
        ps[t] = v + add;
        __syncthreads();
    }
    int run = (t==0) ? 0 : ps[t-1];
    for (int i=0;i<chunk;i++){ off[base0+i]=run; cur[base0+i]=run; run += deg[base0+i]; }
    if (t==255) off[N_NODES] = run;
}
__global__ __launch_bounds__(256) void k_scatter(const int* __restrict__ src, const int* __restrict__ dst,
                                                 const float* __restrict__ dinv, int* __restrict__ cur,
                                                 int* __restrict__ csr_s, float* __restrict__ csr_w){
    int e = blockIdx.x*256 + threadIdx.x;
    if (e < E_EDGES){
        int s = src[e], d = dst[e];
        int p = atomicAdd(&cur[d], 1);
        csr_s[p] = s;
        csr_w[p] = dinv[s]*dinv[d];
    }
}
__global__ __launch_bounds__(256) void k_aggx(const u16* __restrict__ x, const float* __restrict__ dinv,
                                              const int* __restrict__ off, const int* __restrict__ csr_s,
                                              const float* __restrict__ csr_w, float* __restrict__ aggx){
    int n = blockIdx.x*256 + threadIdx.x;
    if (n >= N_NODES) return;
    float di = dinv[n], sw = di*di;
    float a[5];
    #pragma unroll
    for (int k=0;k<5;k++) a[k] = sw * bf2f(x[n*5+k]);
    int j0 = off[n], j1 = off[n+1];
    for (int j=j0;j<j1;j++){
        int s = csr_s[j]; float w = csr_w[j];
        #pragma unroll
        for (int k=0;k<5;k++) a[k] += w * bf2f(x[s*5+k]);
    }
    #pragma unroll
    for (int k=0;k<5;k++) aggx[n*5+k] = a[k];
}
__global__ __launch_bounds__(256) void k_h1(const float* __restrict__ aggx, const u16* __restrict__ W1,
                                            const u16* __restrict__ b1, u16* __restrict__ h1b){
    int id = blockIdx.x*256 + threadIdx.x;      // N*240 exact
    int n = id / HID4; int c4 = (id - n*HID4)*4;
    float a[5];
    #pragma unroll
    for (int k=0;k<5;k++) a[k] = aggx[n*5+k];
    float r0=bf2f(b1[c4+0]), r1=bf2f(b1[c4+1]), r2=bf2f(b1[c4+2]), r3=bf2f(b1[c4+3]);
    #pragma unroll
    for (int k=0;k<5;k++){
        u16x4 wv = *(const u16x4*)(W1 + k*HID + c4);
        r0 += a[k]*bf2f(wv.x); r1 += a[k]*bf2f(wv.y); r2 += a[k]*bf2f(wv.z); r3 += a[k]*bf2f(wv.w);
    }
    r0 = fmaxf(r0,0.f); r1 = fmaxf(r1,0.f); r2 = fmaxf(r2,0.f); r3 = fmaxf(r3,0.f);
    u16x4 o; o.x=f2bf(r0); o.y=f2bf(r1); o.z=f2bf(r2); o.w=f2bf(r3);
    *(u16x4*)(h1b + (size_t)n*HID + c4) = o;
}
__global__ __launch_bounds__(256) void k_p1(const u16* __restrict__ h1b, const float* __restrict__ dinv,
                                            const int* __restrict__ off, const int* __restrict__ csr_s,
                                            const float* __restrict__ csr_w, u16* __restrict__ P1b){
    int id = blockIdx.x*256 + threadIdx.x;      // N*240 exact
    int n = id / HID4; int c4 = (id - n*HID4)*4;
    float di = dinv[n], sw = di*di;
    u16x4 h = *(const u16x4*)(h1b + (size_t)n*HID + c4);
    float s0=sw*bf2f(h.x), s1=sw*bf2f(h.y), s2=sw*bf2f(h.z), s3=sw*bf2f(h.w);
    int j0 = off[n], j1 = off[n+1];
    for (int j=j0;j<j1;j++){
        int s = csr_s[j]; float w = csr_w[j];
        u16x4 v = *(const u16x4*)(h1b + (size_t)s*HID + c4);
        s0 += w*bf2f(v.x); s1 += w*bf2f(v.y); s2 += w*bf2f(v.z); s3 += w*bf2f(v.w);
    }
    u16x4 o; o.x=f2bf(s0); o.y=f2bf(s1); o.z=f2bf(s2); o.w=f2bf(s3);
    *(u16x4*)(P1b + (size_t)n*HID + c4) = o;
}
__global__ __launch_bounds__(256) void k_gm(const u16* __restrict__ P1b, u16* __restrict__ gmb){
    int id = blockIdx.x*256 + threadIdx.x;      // 256*240 exact
    int b = id / HID4; int c4 = (id - b*HID4)*4;
    float s0=0,s1=0,s2=0,s3=0;
    for (int i=0;i<NPM;i++){
        u16x4 v = *(const u16x4*)(P1b + (size_t)(b*NPM+i)*HID + c4);
        s0 += bf2f(v.x); s1 += bf2f(v.y); s2 += bf2f(v.z); s3 += bf2f(v.w);
    }
    const float inv = 1.0f/(float)NPM;
    u16x4 o; o.x=f2bf(s0*inv); o.y=f2bf(s1*inv); o.z=f2bf(s2*inv); o.w=f2bf(s3*inv);
    *(u16x4*)(gmb + (size_t)b*HID + c4) = o;
}
__global__ __launch_bounds__(256) void k_pr(const u16* __restrict__ P1b, const int* __restrict__ fgi,
                                            const int* __restrict__ ptr, u16* __restrict__ prb,
                                            float* __restrict__ evec, u16* __restrict__ maskb,
                                            float* __restrict__ maskf, const int* __restrict__ flag){
    int id = blockIdx.x*256 + threadIdx.x;      // 8192*240 exact
    int bf = id / HID4; int c4 = (id - bf*HID4)*4;
    int b = bf >> 5;
    int base = ptr[b];
    float s0=0,s1=0,s2=0,s3=0; int cnt=0;
    #pragma unroll
    for (int a=0;a<AMAXA;a++){
        int idx = fgi[bf*AMAXA + a];
        if (idx >= 0){
            cnt++;
            u16x4 v = *(const u16x4*)(P1b + (size_t)(base+idx)*HID + c4);
            s0 += bf2f(v.x); s1 += bf2f(v.y); s2 += bf2f(v.z); s3 += bf2f(v.w);
        }
    }
    float inv = (cnt>0) ? 1.0f/(float)cnt : 0.0f;
    u16x4 o; o.x=f2bf(s0*inv); o.y=f2bf(s1*inv); o.z=f2bf(s2*inv); o.w=f2bf(s3*inv);
    *(u16x4*)(prb + (size_t)bf*HID + c4) = o;
    if (c4 == 0){
        float e = (cnt>0) ? 1.0f : 0.0f;
        evec[bf] = e;
        if (*flag) maskf[bf] = e;
        else       maskb[bf] = f2bf(e);
    }
}
__global__ __launch_bounds__(256) void k_transpose(const u16* __restrict__ src, u16* __restrict__ dst, int R, int C){
    __shared__ __attribute__((aligned(16))) u16 t[32][33];
    int c0 = blockIdx.x*32, r0 = blockIdx.y*32;
    int tx = threadIdx.x, ty = threadIdx.y;   // 32 x 8
    #pragma unroll
    for (int i=0;i<4;i++) t[ty+i*8][tx] = src[(size_t)(r0+ty+i*8)*C + c0+tx];
    __syncthreads();
    #pragma unroll
    for (int i=0;i<4;i++) dst[(size_t)(c0+ty+i*8)*R + r0+tx] = t[tx][ty+i*8];
}
__global__ __launch_bounds__(256) void k_cast(const u16* __restrict__ in, float* __restrict__ out, int n){
    int i = blockIdx.x*256 + threadIdx.x; if (i<n) out[i] = bf2f(in[i]);
}
// out[c] += sum_k v[k]*M[k*ld+c]  -- split-K, grid (HID/64, 16), out must be pre-zeroed
__global__ __launch_bounds__(256) void k_vecmat(const float* __restrict__ v, const u16* __restrict__ M,
                                                int ld, float* __restrict__ out){
    __shared__ float part[4][64];
    int tid = threadIdx.x;
    int cl = tid & 63;
    int c = blockIdx.x*64 + cl;
    int kg = tid >> 6;
    int k0 = blockIdx.y*60 + kg*15;
    float s = 0.f;
    #pragma unroll
    for (int i=0;i<15;i++){
        int k = k0 + i;
        s += v[k]*bf2f(M[(size_t)k*ld + c]);
    }
    part[kg][cl] = s;
    __syncthreads();
    if (kg==0){
        float r = part[0][cl] + part[1][cl] + part[2][cl] + part[3][cl];
        atomicAdd(&out[c], r);
    }
}
__global__ __launch_bounds__(256) void k_addc(const float* __restrict__ a, const float* __restrict__ b,
                                              const u16* __restrict__ fb, float* __restrict__ out){
    int c = blockIdx.x*256 + threadIdx.x; if (c<HID) out[c] = a[c] + b[c] + bf2f(fb[c]);
}

// ---------------- bf16 MFMA GEMM: C[M,960] = A[M,K] @ Bt[960,K]^T ----------------
template<int FINAL>
__global__ __launch_bounds__(256) void k_gemm(
    const u16* __restrict__ A, int lda,
    const u16* __restrict__ Bt, int ldb,
    float* __restrict__ Cf, u16* __restrict__ Cb, int cbf16,
    int M, int K,
    const int* __restrict__ fg_type, const float* __restrict__ evec,
    const float* __restrict__ fgA, const float* __restrict__ pWbM,
    const float* __restrict__ vb, const float* __restrict__ c0,
    const float* __restrict__ Gc, const int* __restrict__ flag)
{
    __shared__ __attribute__((aligned(16))) u16 As[64*40];
    __shared__ __attribute__((aligned(16))) u16 Bs[64*40];
    const int tid = threadIdx.x;
    const int wave = tid>>6, lane = tid&63;
    const int wm = wave>>1, wn = wave&1;
    const int q = lane>>4, l16 = lane&15;
    const int m0 = blockIdx.x*64, n0 = blockIdx.y*64;
    const int sm = tid>>2, sk = (tid&3)*8;

    f32x4 acc00={0,0,0,0}, acc01={0,0,0,0}, acc10={0,0,0,0}, acc11={0,0,0,0};
    const bool aOk = (m0+sm) < M;
    const u16* Ap = A + (size_t)(m0+sm)*lda + sk;
    const u16* Bp = Bt + (size_t)(n0+sm)*ldb + sk;

    for (int k0=0; k0<K; k0+=32){
        short8 av = {0,0,0,0,0,0,0,0};
        if (aOk) av = *(const short8*)(Ap + k0);
        short8 bv = *(const short8*)(Bp + k0);
        *(short8*)(As + sm*40 + sk) = av;
        *(short8*)(Bs + sm*40 + sk) = bv;
        __syncthreads();
        short8 a0 = *(const short8*)(As + (wm*32      + l16)*40 + q*8);
        short8 a1 = *(const short8*)(As + (wm*32 + 16 + l16)*40 + q*8);
        short8 b0 = *(const short8*)(Bs + (wn*32      + l16)*40 + q*8);
        short8 b1 = *(const short8*)(Bs + (wn*32 + 16 + l16)*40 + q*8);
        acc00 = __builtin_amdgcn_mfma_f32_16x16x32_bf16(a0,b0,acc00,0,0,0);
        acc01 = __builtin_amdgcn_mfma_f32_16x16x32_bf16(a0,b1,acc01,0,0,0);
        acc10 = __builtin_amdgcn_mfma_f32_16x16x32_bf16(a1,b0,acc10,0,0,0);
        acc11 = __builtin_amdgcn_mfma_f32_16x16x32_bf16(a1,b1,acc11,0,0,0);
        __syncthreads();
    }

    int isf = FINAL ? *flag : 0;
    #pragma unroll
    for (int i=0;i<2;i++){
        int rowb = m0 + wm*32 + i*16 + q*4;
        #pragma unroll
        for (int j=0;j<2;j++){
            int col = n0 + wn*32 + j*16 + l16;
            f32x4 av = (i==0) ? ((j==0)?acc00:acc01) : ((j==0)?acc10:acc11);
            #pragma unroll
            for (int r=0;r<4;r++){
                int row = rowb + r;
                if (row >= M) continue;
                float v = av[r];
                if (FINAL){
                    int bb = row>>5, ff = row&31;
                    int ty = fg_type[row];
                    float e = evec[row];
                    v += fgA[ty*HID+col] + pWbM[ff*HID+col] + e*vb[col] + c0[col] + Gc[bb*HID+col];
                    if (isf) Cf[(size_t)row*HID + col] = v;
                    else     Cb[(size_t)row*HID + col] = f2bf(v);
                } else if (cbf16){
                    Cb[(size_t)row*HID + col] = f2bf(v);
                } else {
                    Cf[(size_t)row*HID + col] = v;
                }
            }
        }
    }
}

extern "C" void kernel_launch(void* const* d_in, const int* in_sizes, int n_in,
                              void* d_out, int out_size, void* d_ws, size_t ws_size,
                              hipStream_t stream) {
    const int* edge_idx  = (const int*)d_in[1];
    const int* ptr       = (const int*)d_in[3];
    const int* fg_type   = (const int*)d_in[4];
    const int* fg_idx    = (const int*)d_in[5];

    // ---- workspace layout (aliased lifetimes) ----
    char* w = (char*)d_ws;
    auto nxt = [&](size_t b)->char*{ char* p = w; w += (b + 255) & ~(size_t)255; return p; };
    // big region 0: fuseWT+Ub (early) -> h1b (mid) -> prb (late)
    u16* big0   = (u16*)nxt((size_t)N_NODES*HID*2);       // 31.46 MB
    u16* fuseWT = big0;                                   // [960,2560]
    u16* Ub     = big0 + (size_t)HID*2560;                // [960,960]
    u16* h1b    = big0;                                   // [16384,960]
    u16* prb    = big0;                                   // [8192,960]
    u16* P1b    = (u16*)nxt((size_t)N_NODES*HID*2);       // 31.46 MB
    // persistent
    u16*  WbigT  = (u16*) nxt((size_t)HID*HID*2);
    u16*  WglobT = (u16*) nxt((size_t)HID*HID*2);
    float* fgA   = (float*)nxt((size_t)NFG*HID*4);
    float* pWbM  = (float*)nxt((size_t)FMAXF*HID*4);
    float* b2f   = (float*)nxt(HID*4);
    float* projbf= (float*)nxt(HID*4);
    float* tvb   = (float*)nxt(HID*4);   // tvb, vb, cC, gvec contiguous (960*4 = 15*256 bytes)
    float* vb    = (float*)nxt(HID*4);
    float* cC    = (float*)nxt(HID*4);
    float* gvec  = (float*)nxt(HID*4);
    float* c0    = (float*)nxt(HID*4);
    int*   deg   = (int*)  nxt(N_NODES*4);
    float* dinv  = (float*)nxt(N_NODES*4);
    int*   off   = (int*)  nxt((N_NODES+1)*4);
    int*   cur   = (int*)  nxt(N_NODES*4);
    int*   csr_s = (int*)  nxt(E_EDGES*4);
    float* csr_w = (float*)nxt(E_EDGES*4);
    float* aggx  = (float*)nxt((size_t)N_NODES*5*4);
    float* evec  = (float*)nxt(BF_ROWS*4);
    u16*   gmb   = (u16*)  nxt((size_t)B_MOL*HID*2);
    float* Gc    = (float*)nxt((size_t)B_MOL*HID*4);
    int*   flag  = (int*)  nxt(256);
    // normalized bf16 copies of all float inputs
    u16* gxn    = (u16*)nxt((size_t)N_NODES*5*2);
    u16* W1n    = (u16*)nxt((size_t)5*HID*2);
    u16* b1n    = (u16*)nxt((size_t)HID*2);
    u16* W2n    = (u16*)nxt((size_t)HID*HID*2);
    u16* b2n    = (u16*)nxt((size_t)HID*2);
    u16* fgeN   = (u16*)nxt((size_t)NFG*512*2);
    u16* posN   = (u16*)nxt((size_t)160*128*2);
    u16* projWn = (u16*)nxt((size_t)HID*HID*2);
    u16* projbn = (u16*)nxt((size_t)HID*2);
    u16* fuseWn = (u16*)nxt((size_t)2560*HID*2);
    u16* fusebn = (u16*)nxt((size_t)HID*2);

    // ---- dtype detect + normalize ----
    k_detect<<<1,256,0,stream>>>((const u16*)d_in[0], flag);
    auto norm = [&](const void* s, u16* d, int n){ k_norm<<<(n+255)/256,256,0,stream>>>(s, d, n, flag); };
    norm(d_in[0],  gxn,    N_NODES*5);
    norm(d_in[6],  W1n,    5*HID);
    norm(d_in[7],  b1n,    HID);
    norm(d_in[8],  W2n,    HID*HID);
    norm(d_in[9],  b2n,    HID);
    norm(d_in[10], fgeN,   NFG*512);
    norm(d_in[11], posN,   160*128);
    norm(d_in[12], projWn, HID*HID);
    norm(d_in[13], projbn, HID);
    norm(d_in[14], fuseWn, 2560*HID);
    norm(d_in[15], fusebn, HID);

    const int* fl = flag;
    #define GEMM_TAIL nullptr,nullptr,nullptr,nullptr,nullptr,nullptr,nullptr,fl

    // ---- weight precompute path ----
    k_transpose<<<dim3(HID/32, 2560/32), dim3(32,8), 0, stream>>>(fuseWn, fuseWT, 2560, HID);
    k_gemm<0><<<dim3(15,15),256,0,stream>>>(fuseWT+640, 2560, projWn, HID, nullptr, Ub, 1, HID, HID, GEMM_TAIL);
    k_gemm<0><<<dim3(15,15),256,0,stream>>>(Ub, HID, W2n, HID, nullptr, WbigT, 1, HID, HID, GEMM_TAIL);
    k_gemm<0><<<dim3(15,15),256,0,stream>>>(fuseWT+1600, 2560, W2n, HID, nullptr, WglobT, 1, HID, HID, GEMM_TAIL);
    k_gemm<0><<<dim3(4,15),256,0,stream>>>(fgeN, 512, fuseWT, 2560, fgA, nullptr, 0, NFG, 512, GEMM_TAIL);
    k_gemm<0><<<dim3(1,15),256,0,stream>>>(posN, 128, fuseWT+512, 2560, pWbM, nullptr, 0, FMAXF, 128, GEMM_TAIL);
    // bias vectors: tvb = b2@projW; vb = tvb@Wc; cC = projb@Wc; gvec = b2@Wd; c0 = cC+gvec+fuseb
    k_cast<<<4,256,0,stream>>>(b2n, b2f, HID);
    k_cast<<<4,256,0,stream>>>(projbn, projbf, HID);
    k_zero<<<15,256,0,stream>>>((int*)tvb, 4*HID);                 // zero tvb,vb,cC,gvec (contiguous)
    k_vecmat<<<dim3(15,16),256,0,stream>>>(b2f,   projWn,           HID, tvb);
    k_vecmat<<<dim3(15,16),256,0,stream>>>(tvb,   fuseWn + 640*HID, HID, vb);
    k_vecmat<<<dim3(15,16),256,0,stream>>>(projbf,fuseWn + 640*HID, HID, cC);
    k_vecmat<<<dim3(15,16),256,0,stream>>>(b2f,   fuseWn + 1600*HID,HID, gvec);
    k_addc<<<4,256,0,stream>>>(cC, gvec, fusebn, c0);

    // ---- graph path ----
    k_zero<<<64,256,0,stream>>>(deg, N_NODES);
    k_hist<<<256,256,0,stream>>>(edge_idx + E_EDGES, deg);
    k_dinv<<<64,256,0,stream>>>(deg, dinv);
    k_scan<<<1,256,0,stream>>>(deg, off, cur);
    k_scatter<<<256,256,0,stream>>>(edge_idx, edge_idx + E_EDGES, dinv, cur, csr_s, csr_w);
    k_aggx<<<64,256,0,stream>>>(gxn, dinv, off, csr_s, csr_w, aggx);
    k_h1<<<15360,256,0,stream>>>(aggx, W1n, b1n, h1b);          // overwrites fuseWT/Ub (dead)
    k_p1<<<15360,256,0,stream>>>(h1b, dinv, off, csr_s, csr_w, P1b);
    k_gm<<<240,256,0,stream>>>(P1b, gmb);
    k_pr<<<7680,256,0,stream>>>(P1b, fg_idx, ptr, prb,          // overwrites h1b (dead)
                                evec, (u16*)d_out + OUT1, (float*)d_out + OUT1, flag);

    // Gc = gm @ (W2 Wd)
    k_gemm<0><<<dim3(4,15),256,0,stream>>>(gmb, HID, WglobT, HID, Gc, nullptr, 0, B_MOL, HID, GEMM_TAIL);
    // out = pr @ (W2 projW Wc) + epilogue
    k_gemm<1><<<dim3(128,15),256,0,stream>>>(prb, HID, WbigT, HID, (float*)d_out, (u16*)d_out, 0, BF_ROWS, HID,
                                             fg_type, evec, fgA, pWbM, vb, c0, Gc, flag);
    (void)in_sizes; (void)n_in; (void)out_size; (void)ws_size;
}

// Round 4
// 334.547 us; speedup vs baseline: 3.5386x; 1.1659x over previous
//
#include <hip/hip_runtime.h>

typedef unsigned short u16;
typedef unsigned int u32;
typedef __attribute__((ext_vector_type(8))) short short8;
typedef __attribute__((ext_vector_type(4))) float f32x4;
typedef __attribute__((ext_vector_type(4))) u16 u16x4;

#define N_NODES 16384
#define B_MOL   256
#define NPM     64
#define E_EDGES 65536
#define FMAXF   32
#define AMAXA   16
#define HID     960
#define NFG     205
#define BF_ROWS 8192
#define OUT1    7864320   // B*FMAX*HID
#define NTOT    4516800   // total normalized elements

__device__ __forceinline__ float bf2f(u16 u){ u32 x=((u32)u)<<16; float f; __builtin_memcpy(&f,&x,4); return f; }
__device__ __forceinline__ u16 f2bf(float f){ u32 x; __builtin_memcpy(&x,&f,4); x += 0x7FFFu + ((x>>16)&1u); return (u16)(x>>16); }

__device__ __forceinline__ void gload_lds16(const u16* g, u16* l){
    __builtin_amdgcn_global_load_lds(
        (const __attribute__((address_space(1))) void*)g,
        (__attribute__((address_space(3))) void*)l, 16, 0, 0);
}

// ---------- dtype detection ----------
__global__ __launch_bounds__(256) void k_detect(const u16* __restrict__ gx, int* __restrict__ flag){
    __shared__ int cnt;
    if (threadIdx.x==0) cnt = 0;
    __syncthreads();
    u16 v = gx[threadIdx.x*2];
    int e = (v>>7) & 0xFF;
    if (e >= 0xC0) atomicAdd(&cnt, 1);
    __syncthreads();
    if (threadIdx.x==0) *flag = (cnt > 16) ? 1 : 0;   // 1 => inputs are fp32
}

struct NormSrcs { const void* p[11]; };
// all 11 float tensors -> one contiguous bf16 region
__global__ __launch_bounds__(256) void k_normAll(NormSrcs s, u16* __restrict__ region, const int* __restrict__ flag){
    int i = blockIdx.x*256 + threadIdx.x;
    if (i >= NTOT) return;
    int seg, off;
    if      (i <   81920){seg=0;  off=i;}
    else if (i <   86720){seg=1;  off=i-81920;}
    else if (i <   87680){seg=2;  off=i-86720;}
    else if (i < 1009280){seg=3;  off=i-87680;}
    else if (i < 1010240){seg=4;  off=i-1009280;}
    else if (i < 1115200){seg=5;  off=i-1010240;}
    else if (i < 1135680){seg=6;  off=i-1115200;}
    else if (i < 2057280){seg=7;  off=i-1135680;}
    else if (i < 2058240){seg=8;  off=i-2057280;}
    else if (i < 4515840){seg=9;  off=i-2058240;}
    else                 {seg=10; off=i-4515840;}
    const void* sp = s.p[seg];
    region[i] = (*flag) ? f2bf(((const float*)sp)[off]) : ((const u16*)sp)[off];
}

// ---------------- utility kernels ----------------
__global__ __launch_bounds__(256) void k_zero(int* p, int n){
    int i = blockIdx.x*256 + threadIdx.x; if (i < n) p[i] = 0;
}
__global__ __launch_bounds__(256) void k_hist(const int* __restrict__ dst, int* __restrict__ deg){
    int e = blockIdx.x*256 + threadIdx.x; if (e < E_EDGES) atomicAdd(&deg[dst[e]], 1);
}
// exclusive scan over 16384 degrees + dinv
__global__ __launch_bounds__(256) void k_scandinv(const int* __restrict__ deg, int* __restrict__ off,
                                                  int* __restrict__ cur, float* __restrict__ dinv){
    __shared__ int ps[256];
    int t = threadIdx.x;
    const int chunk = N_NODES/256; // 64
    int base0 = t*chunk;
    int s = 0;
    for (int i=0;i<chunk;i++) s += deg[base0+i];
    ps[t] = s; __syncthreads();
    for (int ofs=1; ofs<256; ofs<<=1){
        int v = ps[t];
        int add = (t>=ofs) ? ps[t-ofs] : 0;
        __syncthreads();
        ps[t] = v + add;
        __syncthreads();
    }
    int run = (t==0) ? 0 : ps[t-1];
    for (int i=0;i<chunk;i++){
        int d = deg[base0+i];
        off[base0+i]=run; cur[base0+i]=run; run += d;
        dinv[base0+i] = rsqrtf(1.0f + (float)d);
    }
    if (t==255) off[N_NODES] = run;
}
__global__ __launch_bounds__(256) void k_scatter(const int* __restrict__ src, const int* __restrict__ dst,
                                                 const float* __restrict__ dinv, int* __restrict__ cur,
                                                 int* __restrict__ csr_s, float* __restrict__ csr_w){
    int e = blockIdx.x*256 + threadIdx.x;
    if (e < E_EDGES){
        int s = src[e], d = dst[e];
        int p = atomicAdd(&cur[d], 1);
        csr_s[p] = s;
        csr_w[p] = dinv[s]*dinv[d];
    }
}
__global__ __launch_bounds__(256) void k_aggx(const u16* __restrict__ x, const float* __restrict__ dinv,
                                              const int* __restrict__ off, const int* __restrict__ csr_s,
                                              const float* __restrict__ csr_w, float* __restrict__ aggx){
    int n = blockIdx.x*256 + threadIdx.x;
    if (n >= N_NODES) return;
    float di = dinv[n], sw = di*di;
    float a[5];
    #pragma unroll
    for (int k=0;k<5;k++) a[k] = sw * bf2f(x[n*5+k]);
    int j0 = off[n], j1 = off[n+1];
    for (int j=j0;j<j1;j++){
        int s = csr_s[j]; float w = csr_w[j];
        #pragma unroll
        for (int k=0;k<5;k++) a[k] += w * bf2f(x[s*5+k]);
    }
    #pragma unroll
    for (int k=0;k<5;k++) aggx[n*5+k] = a[k];
}
// h1 = relu(aggx @ W1 + b1), c8 layout
__global__ __launch_bounds__(256) void k_h1(const float* __restrict__ aggx, const u16* __restrict__ W1,
                                            const u16* __restrict__ b1, u16* __restrict__ h1b){
    int id = blockIdx.x*256 + threadIdx.x;      // N*120 exact
    int n = id / 120; int c8 = (id - n*120)*8;
    float a[5];
    #pragma unroll
    for (int k=0;k<5;k++) a[k] = aggx[n*5+k];
    float r[8];
    short8 bb = *(const short8*)(b1 + c8);
    #pragma unroll
    for (int j=0;j<8;j++) r[j] = bf2f(((u16*)&bb)[j]);
    #pragma unroll
    for (int k=0;k<5;k++){
        short8 wv = *(const short8*)(W1 + k*HID + c8);
        #pragma unroll
        for (int j=0;j<8;j++) r[j] += a[k]*bf2f(((u16*)&wv)[j]);
    }
    short8 o;
    #pragma unroll
    for (int j=0;j<8;j++) ((u16*)&o)[j] = f2bf(fmaxf(r[j],0.f));
    *(short8*)(h1b + (size_t)n*HID + c8) = o;
}
// P1 = A_norm @ h1 : one block per node, neighbor list staged in LDS
__global__ __launch_bounds__(128) void k_p1(const u16* __restrict__ h1b, const float* __restrict__ dinv,
                                            const int* __restrict__ off, const int* __restrict__ csr_s,
                                            const float* __restrict__ csr_w, u16* __restrict__ P1b){
    __shared__ int   si[64];
    __shared__ float swt[64];
    int n = blockIdx.x, t = threadIdx.x;
    int j0 = off[n], j1 = off[n+1];
    float di = dinv[n], sw = di*di;
    int c8 = t*8;
    float acc[8] = {0,0,0,0,0,0,0,0};
    if (t < 120){
        short8 h = *(const short8*)(h1b + (size_t)n*HID + c8);
        #pragma unroll
        for (int j=0;j<8;j++) acc[j] = sw*bf2f(((u16*)&h)[j]);
    }
    for (int base=j0; base<j1; base+=64){
        int m = min(64, j1-base);
        if (t < m){ si[t] = csr_s[base+t]; swt[t] = csr_w[base+t]; }
        __syncthreads();
        if (t < 120){
            for (int e=0;e<m;e++){
                int s = si[e]; float w = swt[e];
                short8 v = *(const short8*)(h1b + (size_t)s*HID + c8);
                #pragma unroll
                for (int j=0;j<8;j++) acc[j] += w*bf2f(((u16*)&v)[j]);
            }
        }
        __syncthreads();
    }
    if (t < 120){
        short8 o;
        #pragma unroll
        for (int j=0;j<8;j++) ((u16*)&o)[j] = f2bf(acc[j]);
        *(short8*)(P1b + (size_t)n*HID + c8) = o;
    }
}
// gm[b] = mean over 64 nodes, c8 layout
__global__ __launch_bounds__(128) void k_gm(const u16* __restrict__ P1b, u16* __restrict__ gmb){
    int id = blockIdx.x*128 + threadIdx.x;      // 256*120 exact
    int b = id / 120; int c8 = (id - b*120)*8;
    float s[8] = {0,0,0,0,0,0,0,0};
    for (int i=0;i<NPM;i++){
        short8 v = *(const short8*)(P1b + (size_t)(b*NPM+i)*HID + c8);
        #pragma unroll
        for (int j=0;j<8;j++) s[j] += bf2f(((u16*)&v)[j]);
    }
    const float inv = 1.0f/(float)NPM;
    short8 o;
    #pragma unroll
    for (int j=0;j<8;j++) ((u16*)&o)[j] = f2bf(s[j]*inv);
    *(short8*)(gmb + (size_t)b*HID + c8) = o;
}
// pr[bf]: one block per (mol,fg), indices staged in LDS
__global__ __launch_bounds__(128) void k_pr(const u16* __restrict__ P1b, const int* __restrict__ fgi,
                                            const int* __restrict__ ptr, u16* __restrict__ prb,
                                            float* __restrict__ evec, u16* __restrict__ maskb,
                                            float* __restrict__ maskf, const int* __restrict__ flag){
    __shared__ int si[16];
    int bf = blockIdx.x, t = threadIdx.x;
    if (t < 16) si[t] = fgi[bf*AMAXA + t];
    __syncthreads();
    int b = bf >> 5;
    int base = ptr[b];
    int cnt = 0;
    float acc[8] = {0,0,0,0,0,0,0,0};
    int c8 = t*8;
    #pragma unroll
    for (int a=0;a<AMAXA;a++){
        int idx = si[a];
        if (idx >= 0){
            cnt++;
            if (t < 120){
                short8 v = *(const short8*)(P1b + (size_t)(base+idx)*HID + c8);
                #pragma unroll
                for (int j=0;j<8;j++) acc[j] += bf2f(((u16*)&v)[j]);
            }
        }
    }
    float inv = (cnt>0) ? 1.0f/(float)cnt : 0.0f;
    if (t < 120){
        short8 o;
        #pragma unroll
        for (int j=0;j<8;j++) ((u16*)&o)[j] = f2bf(acc[j]*inv);
        *(short8*)(prb + (size_t)bf*HID + c8) = o;
    }
    if (t == 0){
        float e = (cnt>0) ? 1.0f : 0.0f;
        evec[bf] = e;
        if (*flag) maskf[bf] = e;
        else       maskb[bf] = f2bf(e);
    }
}
__global__ __launch_bounds__(256) void k_transpose(const u16* __restrict__ src, u16* __restrict__ dst, int R, int C){
    __shared__ __attribute__((aligned(16))) u16 t[32][33];
    int c0 = blockIdx.x*32, r0 = blockIdx.y*32;
    int tx = threadIdx.x, ty = threadIdx.y;   // 32 x 8
    #pragma unroll
    for (int i=0;i<4;i++) t[ty+i*8][tx] = src[(size_t)(r0+ty+i*8)*C + c0+tx];
    __syncthreads();
    #pragma unroll
    for (int i=0;i<4;i++) dst[(size_t)(c0+ty+i*8)*R + r0+tx] = t[tx][ty+i*8];
}
// prep: cast b2/projb to fp32, zero tvb..gvec (4*960 floats contiguous)
__global__ __launch_bounds__(256) void k_prep(const u16* __restrict__ b2n, const u16* __restrict__ projbn,
                                              float* __restrict__ b2f, float* __restrict__ projbf,
                                              float* __restrict__ z4){
    int i = blockIdx.x*256 + threadIdx.x;   // 3840
    if (i < HID){ b2f[i] = bf2f(b2n[i]); projbf[i] = bf2f(projbn[i]); }
    z4[i] = 0.f;
}
// split-K vec-mat (+= into pre-zeroed out), grid (15,16)
__device__ __forceinline__ void vecmat_body(const float* v, const u16* M, float* out){
    __shared__ float part[4][64];
    int tid = threadIdx.x;
    int cl = tid & 63;
    int c = blockIdx.x*64 + cl;
    int kg = tid >> 6;
    int k0 = blockIdx.y*60 + kg*15;
    float s = 0.f;
    #pragma unroll
    for (int i=0;i<15;i++){
        int k = k0 + i;
        s += v[k]*bf2f(M[(size_t)k*HID + c]);
    }
    part[kg][cl] = s;
    __syncthreads();
    if (kg==0){
        float r = part[0][cl] + part[1][cl] + part[2][cl] + part[3][cl];
        atomicAdd(&out[c], r);
    }
}
__global__ __launch_bounds__(256) void k_vecmat(const float* __restrict__ v, const u16* __restrict__ M,
                                                float* __restrict__ out){
    vecmat_body(v, M, out);
}
__global__ __launch_bounds__(256) void k_vecmat3(const float* s0, const float* s1, const float* s2,
                                                 const u16* M0, const u16* M1, const u16* M2,
                                                 float* o0, float* o1, float* o2){
    const float* v; const u16* M; float* out;
    if (blockIdx.z==0){v=s0;M=M0;out=o0;}
    else if (blockIdx.z==1){v=s1;M=M1;out=o1;}
    else {v=s2;M=M2;out=o2;}
    vecmat_body(v, M, out);
}
__global__ __launch_bounds__(256) void k_addc(const float* __restrict__ a, const float* __restrict__ b,
                                              const u16* __restrict__ fb, float* __restrict__ out){
    int c = blockIdx.x*256 + threadIdx.x; if (c<HID) out[c] = a[c] + b[c] + bf2f(fb[c]);
}

// ---------------- generic 64x64 GEMM, fp32 out: C[M,960] = A[M,K] @ Bt[960,K]^T ----------------
__global__ __launch_bounds__(256) void k_gemm(
    const u16* __restrict__ A, int lda, const u16* __restrict__ Bt, int ldb,
    float* __restrict__ C, int M, int K)
{
    __shared__ __attribute__((aligned(16))) u16 As[64*40];
    __shared__ __attribute__((aligned(16))) u16 Bs[64*40];
    const int tid = threadIdx.x;
    const int wave = tid>>6, lane = tid&63;
    const int wm = wave>>1, wn = wave&1;
    const int q = lane>>4, l16 = lane&15;
    const int m0 = blockIdx.x*64, n0 = blockIdx.y*64;
    const int sm = tid>>2, sk = (tid&3)*8;

    f32x4 acc00={0,0,0,0}, acc01={0,0,0,0}, acc10={0,0,0,0}, acc11={0,0,0,0};
    const bool aOk = (m0+sm) < M;
    const u16* Ap = A + (size_t)(m0+sm)*lda + sk;
    const u16* Bp = Bt + (size_t)(n0+sm)*ldb + sk;

    for (int k0=0; k0<K; k0+=32){
        short8 av = {0,0,0,0,0,0,0,0};
        if (aOk) av = *(const short8*)(Ap + k0);
        short8 bv = *(const short8*)(Bp + k0);
        *(short8*)(As + sm*40 + sk) = av;
        *(short8*)(Bs + sm*40 + sk) = bv;
        __syncthreads();
        short8 a0 = *(const short8*)(As + (wm*32      + l16)*40 + q*8);
        short8 a1 = *(const short8*)(As + (wm*32 + 16 + l16)*40 + q*8);
        short8 b0 = *(const short8*)(Bs + (wn*32      + l16)*40 + q*8);
        short8 b1 = *(const short8*)(Bs + (wn*32 + 16 + l16)*40 + q*8);
        acc00 = __builtin_amdgcn_mfma_f32_16x16x32_bf16(a0,b0,acc00,0,0,0);
        acc01 = __builtin_amdgcn_mfma_f32_16x16x32_bf16(a0,b1,acc01,0,0,0);
        acc10 = __builtin_amdgcn_mfma_f32_16x16x32_bf16(a1,b0,acc10,0,0,0);
        acc11 = __builtin_amdgcn_mfma_f32_16x16x32_bf16(a1,b1,acc11,0,0,0);
        __syncthreads();
    }
    #pragma unroll
    for (int i=0;i<2;i++){
        int rowb = m0 + wm*32 + i*16 + q*4;
        #pragma unroll
        for (int j=0;j<2;j++){
            int col = n0 + wn*32 + j*16 + l16;
            f32x4 av = (i==0) ? ((j==0)?acc00:acc01) : ((j==0)?acc10:acc11);
            #pragma unroll
            for (int r=0;r<4;r++){
                int row = rowb + r;
                if (row < M) C[(size_t)row*HID + col] = av[r];
            }
        }
    }
}

// ---------------- square 960 GEMM, bf16 out, z-batched pair ----------------
__global__ __launch_bounds__(256) void k_gemmS(
    const u16* A0, const u16* A1, int lda,
    const u16* B0, const u16* B1, int ldb,
    u16* C0, u16* C1)
{
    const u16* A  = blockIdx.z ? A1 : A0;
    const u16* Bt = blockIdx.z ? B1 : B0;
    u16* C        = blockIdx.z ? C1 : C0;
    __shared__ __attribute__((aligned(16))) u16 As[64*40];
    __shared__ __attribute__((aligned(16))) u16 Bs[64*40];
    const int tid = threadIdx.x;
    const int wave = tid>>6, lane = tid&63;
    const int wm = wave>>1, wn = wave&1;
    const int q = lane>>4, l16 = lane&15;
    const int m0 = blockIdx.x*64, n0 = blockIdx.y*64;
    const int sm = tid>>2, sk = (tid&3)*8;

    f32x4 acc00={0,0,0,0}, acc01={0,0,0,0}, acc10={0,0,0,0}, acc11={0,0,0,0};
    const u16* Ap = A + (size_t)(m0+sm)*lda + sk;
    const u16* Bp = Bt + (size_t)(n0+sm)*ldb + sk;

    for (int k0=0; k0<HID; k0+=32){
        short8 av = *(const short8*)(Ap + k0);
        short8 bv = *(const short8*)(Bp + k0);
        *(short8*)(As + sm*40 + sk) = av;
        *(short8*)(Bs + sm*40 + sk) = bv;
        __syncthreads();
        short8 a0 = *(const short8*)(As + (wm*32      + l16)*40 + q*8);
        short8 a1 = *(const short8*)(As + (wm*32 + 16 + l16)*40 + q*8);
        short8 b0 = *(const short8*)(Bs + (wn*32      + l16)*40 + q*8);
        short8 b1 = *(const short8*)(Bs + (wn*32 + 16 + l16)*40 + q*8);
        acc00 = __builtin_amdgcn_mfma_f32_16x16x32_bf16(a0,b0,acc00,0,0,0);
        acc01 = __builtin_amdgcn_mfma_f32_16x16x32_bf16(a0,b1,acc01,0,0,0);
        acc10 = __builtin_amdgcn_mfma_f32_16x16x32_bf16(a1,b0,acc10,0,0,0);
        acc11 = __builtin_amdgcn_mfma_f32_16x16x32_bf16(a1,b1,acc11,0,0,0);
        __syncthreads();
    }
    #pragma unroll
    for (int i=0;i<2;i++){
        int rowb = m0 + wm*32 + i*16 + q*4;
        #pragma unroll
        for (int j=0;j<2;j++){
            int col = n0 + wn*32 + j*16 + l16;
            f32x4 av = (i==0) ? ((j==0)?acc00:acc01) : ((j==0)?acc10:acc11);
            #pragma unroll
            for (int r=0;r<4;r++) C[(size_t)(rowb+r)*HID + col] = f2bf(av[r]);
        }
    }
}

// ------- final GEMM: out[8192,960] = prb @ WbigT^T + epilogue -------
// BM=128, BN=96, BK=32; fragment-linear LDS + global_load_lds(16B)
__global__ __launch_bounds__(256) void k_gemmF(
    const u16* __restrict__ A, const u16* __restrict__ Bt,
    float* __restrict__ Cf, u16* __restrict__ Cb,
    const int* __restrict__ fg_type, const float* __restrict__ evec,
    const float* __restrict__ fgA, const float* __restrict__ pWbM,
    const float* __restrict__ vb, const float* __restrict__ c0,
    const float* __restrict__ Gc, const int* __restrict__ flag)
{
    __shared__ __attribute__((aligned(16))) u16 As[8*512];   // 8 frag-regions x (64 lanes x 8 bf16)
    __shared__ __attribute__((aligned(16))) u16 Bs[6*512];
    const int tid = threadIdx.x;
    const int wave = tid>>6, lane = tid&63;
    const int wm = wave>>1, wn = wave&1;
    const int q = lane>>4, l16 = lane&15;
    const int m0 = blockIdx.x*128, n0 = blockIdx.y*96;

    f32x4 acc[4][3];
    #pragma unroll
    for (int i=0;i<4;i++)
        #pragma unroll
        for (int j=0;j<3;j++) acc[i][j] = (f32x4){0,0,0,0};

    const int fiA = wave*2;
    const u16* gA0 = A + (size_t)(m0 + fiA*16     + l16)*HID + q*8;
    const u16* gA1 = A + (size_t)(m0 + fiA*16 +16 + l16)*HID + q*8;
    const u16* gB0 = Bt + (size_t)(n0 + wave*16   + l16)*HID + q*8;
    const u16* gB1 = Bt + (size_t)(n0 + (wave+4)*16 + l16)*HID + q*8;  // only wave<2

    for (int k0=0; k0<HID; k0+=32){
        gload_lds16(gA0 + k0, As + fiA*512);
        gload_lds16(gA1 + k0, As + (fiA+1)*512);
        gload_lds16(gB0 + k0, Bs + wave*512);
        if (wave < 2) gload_lds16(gB1 + k0, Bs + (wave+4)*512);
        __syncthreads();
        short8 af[4], bfr[3];
        #pragma unroll
        for (int i=0;i<4;i++) af[i] = *(const short8*)(As + ((wm*4+i)*64 + lane)*8);
        #pragma unroll
        for (int j=0;j<3;j++) bfr[j] = *(const short8*)(Bs + ((wn*3+j)*64 + lane)*8);
        #pragma unroll
        for (int i=0;i<4;i++)
            #pragma unroll
            for (int j=0;j<3;j++)
                acc[i][j] = __builtin_amdgcn_mfma_f32_16x16x32_bf16(af[i], bfr[j], acc[i][j], 0,0,0);
        __syncthreads();
    }

    const int isf = *flag;
    #pragma unroll
    for (int i=0;i<4;i++){
        int rowb = m0 + wm*64 + i*16 + q*4;
        #pragma unroll
        for (int r=0;r<4;r++){
            int row = rowb + r;
            int bb = row>>5, ff = row&31;
            int ty = fg_type[row];
            float e = evec[row];
            #pragma unroll
            for (int j=0;j<3;j++){
                int col = n0 + wn*48 + j*16 + l16;
                float v = acc[i][j][r]
                        + fgA[ty*HID+col] + pWbM[ff*HID+col]
                        + e*vb[col] + c0[col] + Gc[bb*HID+col];
                if (isf) Cf[(size_t)row*HID + col] = v;
                else     Cb[(size_t)row*HID + col] = f2bf(v);
            }
        }
    }
}

extern "C" void kernel_launch(void* const* d_in, const int* in_sizes, int n_in,
                              void* d_out, int out_size, void* d_ws, size_t ws_size,
                              hipStream_t stream) {
    const int* edge_idx  = (const int*)d_in[1];
    const int* ptr       = (const int*)d_in[3];
    const int* fg_type   = (const int*)d_in[4];
    const int* fg_idx    = (const int*)d_in[5];

    // ---- workspace layout ----
    char* w = (char*)d_ws;
    auto nxt = [&](size_t b)->char*{ char* p = w; w += (b + 255) & ~(size_t)255; return p; };
    u16* big0   = (u16*)nxt((size_t)N_NODES*HID*2);       // fuseWT+Ub -> h1b -> prb
    u16* fuseWT = big0;
    u16* Ub     = big0 + (size_t)HID*2560;
    u16* h1b    = big0;
    u16* prb    = big0;
    u16* P1b    = (u16*)nxt((size_t)N_NODES*HID*2);
    u16*  WbigT  = (u16*) nxt((size_t)HID*HID*2);
    u16*  WglobT = (u16*) nxt((size_t)HID*HID*2);
    float* fgA   = (float*)nxt((size_t)NFG*HID*4);
    float* pWbM  = (float*)nxt((size_t)FMAXF*HID*4);
    float* b2f   = (float*)nxt(HID*4);
    float* projbf= (float*)nxt(HID*4);
    float* tvb   = (float*)nxt(HID*4);   // tvb, vb, cC, gvec contiguous
    float* vb    = (float*)nxt(HID*4);
    float* cC    = (float*)nxt(HID*4);
    float* gvec  = (float*)nxt(HID*4);
    float* c0    = (float*)nxt(HID*4);
    int*   deg   = (int*)  nxt(N_NODES*4);
    float* dinv  = (float*)nxt(N_NODES*4);
    int*   off   = (int*)  nxt((N_NODES+1)*4);
    int*   cur   = (int*)  nxt(N_NODES*4);
    int*   csr_s = (int*)  nxt(E_EDGES*4);
    float* csr_w = (float*)nxt(E_EDGES*4);
    float* aggx  = (float*)nxt((size_t)N_NODES*5*4);
    float* evec  = (float*)nxt(BF_ROWS*4);
    u16*   gmb   = (u16*)  nxt((size_t)B_MOL*HID*2);
    float* Gc    = (float*)nxt((size_t)B_MOL*HID*4);
    int*   flag  = (int*)  nxt(256);
    u16*   region= (u16*)  nxt((size_t)NTOT*2);
    // views into region
    u16* gxn    = region;
    u16* W1n    = region +   81920;
    u16* b1n    = region +   86720;
    u16* W2n    = region +   87680;
    u16* b2n    = region + 1009280;
    u16* fgeN   = region + 1010240;
    u16* posN   = region + 1115200;
    u16* projWn = region + 1135680;
    u16* projbn = region + 2057280;
    u16* fuseWn = region + 2058240;
    u16* fusebn = region + 4515840;

    // ---- dtype detect + normalize (1 launch) ----
    k_detect<<<1,256,0,stream>>>((const u16*)d_in[0], flag);
    NormSrcs ns;
    ns.p[0]=d_in[0]; ns.p[1]=d_in[6]; ns.p[2]=d_in[7]; ns.p[3]=d_in[8]; ns.p[4]=d_in[9];
    ns.p[5]=d_in[10]; ns.p[6]=d_in[11]; ns.p[7]=d_in[12]; ns.p[8]=d_in[13]; ns.p[9]=d_in[14]; ns.p[10]=d_in[15];
    k_normAll<<<(NTOT+255)/256,256,0,stream>>>(ns, region, flag);

    // ---- weight precompute ----
    k_transpose<<<dim3(HID/32, 2560/32), dim3(32,8), 0, stream>>>(fuseWn, fuseWT, 2560, HID);
    // z=0: Ub = Wc^T @ projW^T ; z=1: WglobT = Wd^T @ W2^T
    k_gemmS<<<dim3(15,15,2),256,0,stream>>>(fuseWT+640, fuseWT+1600, 2560, projWn, W2n, HID, Ub, WglobT);
    // WbigT = Ub @ W2^T
    k_gemmS<<<dim3(15,15,1),256,0,stream>>>(Ub, Ub, HID, W2n, W2n, HID, WbigT, WbigT);
    k_gemm<<<dim3(4,15),256,0,stream>>>(fgeN, 512, fuseWT, 2560, fgA, NFG, 512);
    k_gemm<<<dim3(1,15),256,0,stream>>>(posN, 128, fuseWT+512, 2560, pWbM, FMAXF, 128);
    k_prep<<<15,256,0,stream>>>(b2n, projbn, b2f, projbf, tvb);
    k_vecmat3<<<dim3(15,16,3),256,0,stream>>>(b2f, projbf, b2f,
                                              projWn, fuseWn + 640*HID, fuseWn + 1600*HID,
                                              tvb, cC, gvec);
    k_vecmat<<<dim3(15,16),256,0,stream>>>(tvb, fuseWn + 640*HID, vb);
    k_addc<<<4,256,0,stream>>>(cC, gvec, fusebn, c0);

    // ---- graph path ----
    k_zero<<<64,256,0,stream>>>(deg, N_NODES);
    k_hist<<<256,256,0,stream>>>(edge_idx + E_EDGES, deg);
    k_scandinv<<<1,256,0,stream>>>(deg, off, cur, dinv);
    k_scatter<<<256,256,0,stream>>>(edge_idx, edge_idx + E_EDGES, dinv, cur, csr_s, csr_w);
    k_aggx<<<64,256,0,stream>>>(gxn, dinv, off, csr_s, csr_w, aggx);
    k_h1<<<7680,256,0,stream>>>(aggx, W1n, b1n, h1b);          // overwrites fuseWT/Ub (dead)
    k_p1<<<16384,128,0,stream>>>(h1b, dinv, off, csr_s, csr_w, P1b);
    k_gm<<<240,128,0,stream>>>(P1b, gmb);
    k_pr<<<8192,128,0,stream>>>(P1b, fg_idx, ptr, prb,         // overwrites h1b (dead)
                                evec, (u16*)d_out + OUT1, (float*)d_out + OUT1, flag);

    // Gc = gm @ (W2 Wd)
    k_gemm<<<dim3(4,15),256,0,stream>>>(gmb, HID, WglobT, HID, Gc, B_MOL, HID);
    // final
    k_gemmF<<<dim3(64,10),256,0,stream>>>(prb, WbigT, (float*)d_out, (u16*)d_out,
                                          fg_type, evec, fgA, pWbM, vb, c0, Gc, flag);
    (void)in_sizes; (void)n_in; (void)out_size; (void)ws_size;
}

// Round 5
// 322.575 us; speedup vs baseline: 3.6700x; 1.0371x over previous
//
#include <hip/hip_runtime.h>

typedef unsigned short u16;
typedef unsigned int u32;
typedef __attribute__((ext_vector_type(8))) short short8;
typedef __attribute__((ext_vector_type(4))) float f32x4;

#define N_NODES 16384
#define B_MOL   256
#define NPM     64
#define E_EDGES 65536
#define FMAXF   32
#define AMAXA   16
#define HID     960
#define NFG     205
#define BF_ROWS 8192
#define OUT1    7864320   // B*FMAX*HID
#define NTOT    4516800   // total normalized elements

__device__ __forceinline__ float bf2f(u16 u){ u32 x=((u32)u)<<16; float f; __builtin_memcpy(&f,&x,4); return f; }
__device__ __forceinline__ u16 f2bf(float f){ u32 x; __builtin_memcpy(&x,&f,4); x += 0x7FFFu + ((x>>16)&1u); return (u16)(x>>16); }

__device__ __forceinline__ void gload_lds16(const u16* g, u16* l){
    __builtin_amdgcn_global_load_lds(
        (const __attribute__((address_space(1))) void*)g,
        (__attribute__((address_space(3))) void*)l, 16, 0, 0);
}
// swizzled (fragment-region) address, in u16 units; col multiple of 8
__device__ __forceinline__ size_t swzA(int row, int col){
    return ((size_t)((row>>4)*30 + (col>>5)))*512 + (size_t)(((((col>>3)&3)*16) + (row&15))*8);
}

// ---------- dtype detect + zero deg (fused) ----------
__global__ __launch_bounds__(256) void k_detect(const u16* __restrict__ gx, int* __restrict__ flag,
                                                int* __restrict__ deg){
    int i = blockIdx.x*256 + threadIdx.x;
    if (i < N_NODES) deg[i] = 0;
    if (blockIdx.x == 0){
        __shared__ int cnt;
        if (threadIdx.x==0) cnt = 0;
        __syncthreads();
        u16 v = gx[threadIdx.x*2];
        int e = (v>>7) & 0xFF;
        if (e >= 0xC0) atomicAdd(&cnt, 1);
        __syncthreads();
        if (threadIdx.x==0) *flag = (cnt > 16) ? 1 : 0;   // 1 => inputs are fp32
    }
}

struct NormSrcs { const void* p[11]; };
// all 11 float tensors -> contiguous bf16 region; also b2f/projbf fp32 + zero tvb..gvec
__global__ __launch_bounds__(256) void k_normAll(NormSrcs s, u16* __restrict__ region,
                                                 float* __restrict__ b2f, float* __restrict__ projbf,
                                                 float* __restrict__ z4, const int* __restrict__ flag){
    int i = blockIdx.x*256 + threadIdx.x;
    if (i < 4*HID) z4[i] = 0.f;
    if (i >= NTOT) return;
    int seg, off;
    if      (i <   81920){seg=0;  off=i;}
    else if (i <   86720){seg=1;  off=i-81920;}
    else if (i <   87680){seg=2;  off=i-86720;}
    else if (i < 1009280){seg=3;  off=i-87680;}
    else if (i < 1010240){seg=4;  off=i-1009280;}
    else if (i < 1115200){seg=5;  off=i-1010240;}
    else if (i < 1135680){seg=6;  off=i-1115200;}
    else if (i < 2057280){seg=7;  off=i-1135680;}
    else if (i < 2058240){seg=8;  off=i-2057280;}
    else if (i < 4515840){seg=9;  off=i-2058240;}
    else                 {seg=10; off=i-4515840;}
    const void* sp = s.p[seg];
    float fv; u16 uv;
    if (*flag){ fv = ((const float*)sp)[off]; uv = f2bf(fv); }
    else      { uv = ((const u16*)sp)[off];  fv = bf2f(uv); }
    region[i] = uv;
    if (seg==4) b2f[off] = fv;
    if (seg==8) projbf[off] = fv;
}

// ---------------- graph prep ----------------
__global__ __launch_bounds__(256) void k_hist(const int* __restrict__ dst, int* __restrict__ deg){
    int e = blockIdx.x*256 + threadIdx.x; if (e < E_EDGES) atomicAdd(&deg[dst[e]], 1);
}
__global__ __launch_bounds__(256) void k_scandinv(const int* __restrict__ deg, int* __restrict__ off,
                                                  int* __restrict__ cur, float* __restrict__ dinv){
    __shared__ int ps[256];
    int t = threadIdx.x;
    const int chunk = N_NODES/256; // 64
    int base0 = t*chunk;
    int s = 0;
    for (int i=0;i<chunk;i++) s += deg[base0+i];
    ps[t] = s; __syncthreads();
    for (int ofs=1; ofs<256; ofs<<=1){
        int v = ps[t];
        int add = (t>=ofs) ? ps[t-ofs] : 0;
        __syncthreads();
        ps[t] = v + add;
        __syncthreads();
    }
    int run = (t==0) ? 0 : ps[t-1];
    for (int i=0;i<chunk;i++){
        int d = deg[base0+i];
        off[base0+i]=run; cur[base0+i]=run; run += d;
        dinv[base0+i] = rsqrtf(1.0f + (float)d);
    }
    if (t==255) off[N_NODES] = run;
}
__global__ __launch_bounds__(256) void k_scatter(const int* __restrict__ src, const int* __restrict__ dst,
                                                 const float* __restrict__ dinv, int* __restrict__ cur,
                                                 int* __restrict__ csr_s, float* __restrict__ csr_w){
    int e = blockIdx.x*256 + threadIdx.x;
    if (e < E_EDGES){
        int s = src[e], d = dst[e];
        int p = atomicAdd(&cur[d], 1);
        csr_s[p] = s;
        csr_w[p] = dinv[s]*dinv[d];
    }
}
__global__ __launch_bounds__(256) void k_aggx(const u16* __restrict__ x, const float* __restrict__ dinv,
                                              const int* __restrict__ off, const int* __restrict__ csr_s,
                                              const float* __restrict__ csr_w, float* __restrict__ aggx){
    int n = blockIdx.x*256 + threadIdx.x;
    if (n >= N_NODES) return;
    float di = dinv[n], sw = di*di;
    float a[5];
    #pragma unroll
    for (int k=0;k<5;k++) a[k] = sw * bf2f(x[n*5+k]);
    int j0 = off[n], j1 = off[n+1];
    for (int j=j0;j<j1;j++){
        int s = csr_s[j]; float w = csr_w[j];
        #pragma unroll
        for (int k=0;k<5;k++) a[k] += w * bf2f(x[s*5+k]);
    }
    #pragma unroll
    for (int k=0;k<5;k++) aggx[n*5+k] = a[k];
}
__global__ __launch_bounds__(256) void k_h1(const float* __restrict__ aggx, const u16* __restrict__ W1,
                                            const u16* __restrict__ b1, u16* __restrict__ h1b){
    int id = blockIdx.x*256 + threadIdx.x;      // N*120 exact
    int n = id / 120; int c8 = (id - n*120)*8;
    float a[5];
    #pragma unroll
    for (int k=0;k<5;k++) a[k] = aggx[n*5+k];
    float r[8];
    short8 bb = *(const short8*)(b1 + c8);
    #pragma unroll
    for (int j=0;j<8;j++) r[j] = bf2f(((u16*)&bb)[j]);
    #pragma unroll
    for (int k=0;k<5;k++){
        short8 wv = *(const short8*)(W1 + k*HID + c8);
        #pragma unroll
        for (int j=0;j<8;j++) r[j] += a[k]*bf2f(((u16*)&wv)[j]);
    }
    short8 o;
    #pragma unroll
    for (int j=0;j<8;j++) ((u16*)&o)[j] = f2bf(fmaxf(r[j],0.f));
    *(short8*)(h1b + (size_t)n*HID + c8) = o;
}
// P1 = A_norm @ h1 : one WAVE per node, wave-uniform CSR loop (scalar loads)
__global__ __launch_bounds__(256) void k_p1(const u16* __restrict__ h1b, const float* __restrict__ dinv,
                                            const int* __restrict__ off, const int* __restrict__ csr_s,
                                            const float* __restrict__ csr_w, u16* __restrict__ P1b){
    int wv = threadIdx.x>>6, lane = threadIdx.x&63;
    int n = blockIdx.x*4 + wv;
    int c = lane*16;
    bool act = lane < 60;
    float di = dinv[n], sw = di*di;
    float acc[16];
    if (act){
        short8 h0 = *(const short8*)(h1b + (size_t)n*HID + c);
        short8 h1v = *(const short8*)(h1b + (size_t)n*HID + c + 8);
        #pragma unroll
        for (int j=0;j<8;j++){ acc[j] = sw*bf2f(((u16*)&h0)[j]); acc[8+j] = sw*bf2f(((u16*)&h1v)[j]); }
    } else {
        #pragma unroll
        for (int j=0;j<16;j++) acc[j] = 0.f;
    }
    int j0 = off[n], j1 = off[n+1];
    for (int j=j0;j<j1;j++){
        int s = csr_s[j]; float w = csr_w[j];
        if (act){
            short8 v0 = *(const short8*)(h1b + (size_t)s*HID + c);
            short8 v1 = *(const short8*)(h1b + (size_t)s*HID + c + 8);
            #pragma unroll
            for (int j2=0;j2<8;j2++){ acc[j2] += w*bf2f(((u16*)&v0)[j2]); acc[8+j2] += w*bf2f(((u16*)&v1)[j2]); }
        }
    }
    if (act){
        short8 o0, o1;
        #pragma unroll
        for (int j=0;j<8;j++){ ((u16*)&o0)[j] = f2bf(acc[j]); ((u16*)&o1)[j] = f2bf(acc[8+j]); }
        *(short8*)(P1b + (size_t)n*HID + c) = o0;
        *(short8*)(P1b + (size_t)n*HID + c + 8) = o1;
    }
}
__global__ __launch_bounds__(128) void k_gm(const u16* __restrict__ P1b, u16* __restrict__ gmb){
    int id = blockIdx.x*128 + threadIdx.x;      // 256*120 exact
    int b = id / 120; int c8 = (id - b*120)*8;
    float s[8] = {0,0,0,0,0,0,0,0};
    for (int i=0;i<NPM;i++){
        short8 v = *(const short8*)(P1b + (size_t)(b*NPM+i)*HID + c8);
        #pragma unroll
        for (int j=0;j<8;j++) s[j] += bf2f(((u16*)&v)[j]);
    }
    const float inv = 1.0f/(float)NPM;
    short8 o;
    #pragma unroll
    for (int j=0;j<8;j++) ((u16*)&o)[j] = f2bf(s[j]*inv);
    *(short8*)(gmb + (size_t)b*HID + c8) = o;
}
// pr: one WAVE per (mol,fg); writes prb in SWIZZLED fragment layout
__global__ __launch_bounds__(256) void k_pr(const u16* __restrict__ P1b, const int* __restrict__ fgi,
                                            const int* __restrict__ ptr, u16* __restrict__ prb,
                                            float* __restrict__ evec, u16* __restrict__ maskb,
                                            float* __restrict__ maskf, const int* __restrict__ flag){
    int wv = threadIdx.x>>6, lane = threadIdx.x&63;
    int bf = blockIdx.x*4 + wv;
    int b = bf >> 5;
    int base = ptr[b];
    int c = lane*16;
    bool act = lane < 60;
    float acc[16];
    #pragma unroll
    for (int j=0;j<16;j++) acc[j] = 0.f;
    int cnt = 0;
    #pragma unroll
    for (int a=0;a<AMAXA;a++){
        int idx = fgi[bf*AMAXA + a];
        if (idx >= 0){
            cnt++;
            if (act){
                short8 v0 = *(const short8*)(P1b + (size_t)(base+idx)*HID + c);
                short8 v1 = *(const short8*)(P1b + (size_t)(base+idx)*HID + c + 8);
                #pragma unroll
                for (int j=0;j<8;j++){ acc[j] += bf2f(((u16*)&v0)[j]); acc[8+j] += bf2f(((u16*)&v1)[j]); }
            }
        }
    }
    float inv = (cnt>0) ? 1.0f/(float)cnt : 0.0f;
    if (act){
        short8 o0, o1;
        #pragma unroll
        for (int j=0;j<8;j++){ ((u16*)&o0)[j] = f2bf(acc[j]*inv); ((u16*)&o1)[j] = f2bf(acc[8+j]*inv); }
        *(short8*)(prb + swzA(bf, c)) = o0;
        *(short8*)(prb + swzA(bf, c+8)) = o1;
    }
    if (lane == 0){
        float e = (cnt>0) ? 1.0f : 0.0f;
        evec[bf] = e;
        if (*flag) maskf[bf] = e;
        else       maskb[bf] = f2bf(e);
    }
}
__global__ __launch_bounds__(256) void k_transpose(const u16* __restrict__ src, u16* __restrict__ dst, int R, int C){
    __shared__ __attribute__((aligned(16))) u16 t[32][33];
    int c0 = blockIdx.x*32, r0 = blockIdx.y*32;
    int tx = threadIdx.x, ty = threadIdx.y;   // 32 x 8
    #pragma unroll
    for (int i=0;i<4;i++) t[ty+i*8][tx] = src[(size_t)(r0+ty+i*8)*C + c0+tx];
    __syncthreads();
    #pragma unroll
    for (int i=0;i<4;i++) dst[(size_t)(c0+ty+i*8)*R + r0+tx] = t[tx][ty+i*8];
}
// WbigT row-major -> swizzled fragment layout
__global__ __launch_bounds__(256) void k_repackB(const u16* __restrict__ src, u16* __restrict__ dst){
    int id = blockIdx.x*256 + threadIdx.x;   // 960*120 exact
    int n = id / 120; int k8 = (id - n*120)*8;
    short8 v = *(const short8*)(src + (size_t)n*HID + k8);
    *(short8*)(dst + swzA(n, k8)) = v;
}
// split-K vec-mat (+= into pre-zeroed out), grid (15,16)
__device__ __forceinline__ void vecmat_body(const float* v, const u16* M, float* out){
    __shared__ float part[4][64];
    int tid = threadIdx.x;
    int cl = tid & 63;
    int c = blockIdx.x*64 + cl;
    int kg = tid >> 6;
    int k0 = blockIdx.y*60 + kg*15;
    float s = 0.f;
    #pragma unroll
    for (int i=0;i<15;i++){
        int k = k0 + i;
        s += v[k]*bf2f(M[(size_t)k*HID + c]);
    }
    part[kg][cl] = s;
    __syncthreads();
    if (kg==0){
        float r = part[0][cl] + part[1][cl] + part[2][cl] + part[3][cl];
        atomicAdd(&out[c], r);
    }
}
__global__ __launch_bounds__(256) void k_vecmat(const float* __restrict__ v, const u16* __restrict__ M,
                                                float* __restrict__ out){
    vecmat_body(v, M, out);
}
__global__ __launch_bounds__(256) void k_vecmat3(const float* s0, const float* s1, const float* s2,
                                                 const u16* M0, const u16* M1, const u16* M2,
                                                 float* o0, float* o1, float* o2){
    const float* v; const u16* M; float* out;
    if (blockIdx.z==0){v=s0;M=M0;out=o0;}
    else if (blockIdx.z==1){v=s1;M=M1;out=o1;}
    else {v=s2;M=M2;out=o2;}
    vecmat_body(v, M, out);
}
__global__ __launch_bounds__(256) void k_addc(const float* __restrict__ a, const float* __restrict__ b,
                                              const u16* __restrict__ fb, float* __restrict__ out){
    int c = blockIdx.x*256 + threadIdx.x; if (c<HID) out[c] = a[c] + b[c] + bf2f(fb[c]);
}

// ---------------- generic 64x64 GEMM, fp32 out: C[M,960] = A[M,K] @ Bt[960,K]^T ----------------
__global__ __launch_bounds__(256) void k_gemm(
    const u16* __restrict__ A, int lda, const u16* __restrict__ Bt, int ldb,
    float* __restrict__ C, int M, int K)
{
    __shared__ __attribute__((aligned(16))) u16 As[64*40];
    __shared__ __attribute__((aligned(16))) u16 Bs[64*40];
    const int tid = threadIdx.x;
    const int wave = tid>>6, lane = tid&63;
    const int wm = wave>>1, wn = wave&1;
    const int q = lane>>4, l16 = lane&15;
    const int m0 = blockIdx.x*64, n0 = blockIdx.y*64;
    const int sm = tid>>2, sk = (tid&3)*8;

    f32x4 acc00={0,0,0,0}, acc01={0,0,0,0}, acc10={0,0,0,0}, acc11={0,0,0,0};
    const bool aOk = (m0+sm) < M;
    const u16* Ap = A + (size_t)(m0+sm)*lda + sk;
    const u16* Bp = Bt + (size_t)(n0+sm)*ldb + sk;

    for (int k0=0; k0<K; k0+=32){
        short8 av = {0,0,0,0,0,0,0,0};
        if (aOk) av = *(const short8*)(Ap + k0);
        short8 bv = *(const short8*)(Bp + k0);
        *(short8*)(As + sm*40 + sk) = av;
        *(short8*)(Bs + sm*40 + sk) = bv;
        __syncthreads();
        short8 a0 = *(const short8*)(As + (wm*32      + l16)*40 + q*8);
        short8 a1 = *(const short8*)(As + (wm*32 + 16 + l16)*40 + q*8);
        short8 b0 = *(const short8*)(Bs + (wn*32      + l16)*40 + q*8);
        short8 b1 = *(const short8*)(Bs + (wn*32 + 16 + l16)*40 + q*8);
        acc00 = __builtin_amdgcn_mfma_f32_16x16x32_bf16(a0,b0,acc00,0,0,0);
        acc01 = __builtin_amdgcn_mfma_f32_16x16x32_bf16(a0,b1,acc01,0,0,0);
        acc10 = __builtin_amdgcn_mfma_f32_16x16x32_bf16(a1,b0,acc10,0,0,0);
        acc11 = __builtin_amdgcn_mfma_f32_16x16x32_bf16(a1,b1,acc11,0,0,0);
        __syncthreads();
    }
    #pragma unroll
    for (int i=0;i<2;i++){
        int rowb = m0 + wm*32 + i*16 + q*4;
        #pragma unroll
        for (int j=0;j<2;j++){
            int col = n0 + wn*32 + j*16 + l16;
            f32x4 av = (i==0) ? ((j==0)?acc00:acc01) : ((j==0)?acc10:acc11);
            #pragma unroll
            for (int r=0;r<4;r++){
                int row = rowb + r;
                if (row < M) C[(size_t)row*HID + col] = av[r];
            }
        }
    }
}

// ---------------- square 960 GEMM, bf16 out, z-batched pair ----------------
__global__ __launch_bounds__(256) void k_gemmS(
    const u16* A0, const u16* A1, int lda,
    const u16* B0, const u16* B1, int ldb,
    u16* C0, u16* C1)
{
    const u16* A  = blockIdx.z ? A1 : A0;
    const u16* Bt = blockIdx.z ? B1 : B0;
    u16* C        = blockIdx.z ? C1 : C0;
    __shared__ __attribute__((aligned(16))) u16 As[64*40];
    __shared__ __attribute__((aligned(16))) u16 Bs[64*40];
    const int tid = threadIdx.x;
    const int wave = tid>>6, lane = tid&63;
    const int wm = wave>>1, wn = wave&1;
    const int q = lane>>4, l16 = lane&15;
    const int m0 = blockIdx.x*64, n0 = blockIdx.y*64;
    const int sm = tid>>2, sk = (tid&3)*8;

    f32x4 acc00={0,0,0,0}, acc01={0,0,0,0}, acc10={0,0,0,0}, acc11={0,0,0,0};
    const u16* Ap = A + (size_t)(m0+sm)*lda + sk;
    const u16* Bp = Bt + (size_t)(n0+sm)*ldb + sk;

    for (int k0=0; k0<HID; k0+=32){
        short8 av = *(const short8*)(Ap + k0);
        short8 bv = *(const short8*)(Bp + k0);
        *(short8*)(As + sm*40 + sk) = av;
        *(short8*)(Bs + sm*40 + sk) = bv;
        __syncthreads();
        short8 a0 = *(const short8*)(As + (wm*32      + l16)*40 + q*8);
        short8 a1 = *(const short8*)(As + (wm*32 + 16 + l16)*40 + q*8);
        short8 b0 = *(const short8*)(Bs + (wn*32      + l16)*40 + q*8);
        short8 b1 = *(const short8*)(Bs + (wn*32 + 16 + l16)*40 + q*8);
        acc00 = __builtin_amdgcn_mfma_f32_16x16x32_bf16(a0,b0,acc00,0,0,0);
        acc01 = __builtin_amdgcn_mfma_f32_16x16x32_bf16(a0,b1,acc01,0,0,0);
        acc10 = __builtin_amdgcn_mfma_f32_16x16x32_bf16(a1,b0,acc10,0,0,0);
        acc11 = __builtin_amdgcn_mfma_f32_16x16x32_bf16(a1,b1,acc11,0,0,0);
        __syncthreads();
    }
    #pragma unroll
    for (int i=0;i<2;i++){
        int rowb = m0 + wm*32 + i*16 + q*4;
        #pragma unroll
        for (int j=0;j<2;j++){
            int col = n0 + wn*32 + j*16 + l16;
            f32x4 av = (i==0) ? ((j==0)?acc00:acc01) : ((j==0)?acc10:acc11);
            #pragma unroll
            for (int r=0;r<4;r++) C[(size_t)(rowb+r)*HID + col] = f2bf(av[r]);
        }
    }
}

// ------- final GEMM: out[8192,960] = prb @ WbigS^T + epilogue -------
// BM=128, BN=96, BK=32; BOTH operands pre-swizzled -> coalesced 1KB global_load_lds
__global__ __launch_bounds__(256) void k_gemmF(
    const u16* __restrict__ A, const u16* __restrict__ Bt,
    float* __restrict__ Cf, u16* __restrict__ Cb,
    const int* __restrict__ fg_type, const float* __restrict__ evec,
    const float* __restrict__ fgA, const float* __restrict__ pWbM,
    const float* __restrict__ vb, const float* __restrict__ c0,
    const float* __restrict__ Gc, const int* __restrict__ flag)
{
    __shared__ __attribute__((aligned(16))) u16 As[8*512];
    __shared__ __attribute__((aligned(16))) u16 Bs[6*512];
    const int tid = threadIdx.x;
    const int wave = tid>>6, lane = tid&63;
    const int wm = wave>>1, wn = wave&1;
    const int q = lane>>4, l16 = lane&15;
    const int m0 = blockIdx.x*128, n0 = blockIdx.y*96;
    const int R0 = blockIdx.x*8, N0 = blockIdx.y*6;

    f32x4 acc[4][3];
    #pragma unroll
    for (int i=0;i<4;i++)
        #pragma unroll
        for (int j=0;j<3;j++) acc[i][j] = (f32x4){0,0,0,0};

    const u16* gA0 = A + ((size_t)(R0 + wave*2    )*30)*512 + lane*8;
    const u16* gA1 = A + ((size_t)(R0 + wave*2 + 1)*30)*512 + lane*8;
    const u16* gB0 = Bt + ((size_t)(N0 + wave     )*30)*512 + lane*8;
    const u16* gB1 = Bt + ((size_t)(N0 + 4 + wave )*30)*512 + lane*8;  // only wave<2

    for (int kc=0; kc<30; kc++){
        gload_lds16(gA0 + kc*512, As + (wave*2  )*512);
        gload_lds16(gA1 + kc*512, As + (wave*2+1)*512);
        gload_lds16(gB0 + kc*512, Bs + wave*512);
        if (wave < 2) gload_lds16(gB1 + kc*512, Bs + (4+wave)*512);
        __syncthreads();
        short8 af[4], bfr[3];
        #pragma unroll
        for (int i=0;i<4;i++) af[i] = *(const short8*)(As + ((wm*4+i)*64 + lane)*8);
        #pragma unroll
        for (int j=0;j<3;j++) bfr[j] = *(const short8*)(Bs + ((wn*3+j)*64 + lane)*8);
        #pragma unroll
        for (int i=0;i<4;i++)
            #pragma unroll
            for (int j=0;j<3;j++)
                acc[i][j] = __builtin_amdgcn_mfma_f32_16x16x32_bf16(af[i], bfr[j], acc[i][j], 0,0,0);
        __syncthreads();
    }

    const int isf = *flag;
    #pragma unroll
    for (int i=0;i<4;i++){
        int rowb = m0 + wm*64 + i*16 + q*4;
        #pragma unroll
        for (int r=0;r<4;r++){
            int row = rowb + r;
            int bb = row>>5, ff = row&31;
            int ty = fg_type[row];
            float e = evec[row];
            #pragma unroll
            for (int j=0;j<3;j++){
                int col = n0 + wn*48 + j*16 + l16;
                float v = acc[i][j][r]
                        + fgA[ty*HID+col] + pWbM[ff*HID+col]
                        + e*vb[col] + c0[col] + Gc[bb*HID+col];
                if (isf) Cf[(size_t)row*HID + col] = v;
                else     Cb[(size_t)row*HID + col] = f2bf(v);
            }
        }
    }
}

extern "C" void kernel_launch(void* const* d_in, const int* in_sizes, int n_in,
                              void* d_out, int out_size, void* d_ws, size_t ws_size,
                              hipStream_t stream) {
    const int* edge_idx  = (const int*)d_in[1];
    const int* ptr       = (const int*)d_in[3];
    const int* fg_type   = (const int*)d_in[4];
    const int* fg_idx    = (const int*)d_in[5];

    // ---- workspace layout ----
    char* w = (char*)d_ws;
    auto nxt = [&](size_t b)->char*{ char* p = w; w += (b + 255) & ~(size_t)255; return p; };
    u16* big0   = (u16*)nxt((size_t)N_NODES*HID*2);       // fuseWT+Ub -> h1b -> prb(swizzled)
    u16* fuseWT = big0;
    u16* Ub     = big0 + (size_t)HID*2560;
    u16* h1b    = big0;
    u16* prb    = big0;
    u16* P1b    = (u16*)nxt((size_t)N_NODES*HID*2);
    u16*  WbigT  = (u16*) nxt((size_t)HID*HID*2);
    u16*  WbigS  = (u16*) nxt((size_t)HID*HID*2);
    u16*  WglobT = (u16*) nxt((size_t)HID*HID*2);
    float* fgA   = (float*)nxt((size_t)NFG*HID*4);
    float* pWbM  = (float*)nxt((size_t)FMAXF*HID*4);
    float* b2f   = (float*)nxt(HID*4);
    float* projbf= (float*)nxt(HID*4);
    float* tvb   = (float*)nxt(HID*4);   // tvb, vb, cC, gvec contiguous
    float* vb    = (float*)nxt(HID*4);
    float* cC    = (float*)nxt(HID*4);
    float* gvec  = (float*)nxt(HID*4);
    float* c0    = (float*)nxt(HID*4);
    int*   deg   = (int*)  nxt(N_NODES*4);
    float* dinv  = (float*)nxt(N_NODES*4);
    int*   off   = (int*)  nxt((N_NODES+1)*4);
    int*   cur   = (int*)  nxt(N_NODES*4);
    int*   csr_s = (int*)  nxt(E_EDGES*4);
    float* csr_w = (float*)nxt(E_EDGES*4);
    float* aggx  = (float*)nxt((size_t)N_NODES*5*4);
    float* evec  = (float*)nxt(BF_ROWS*4);
    u16*   gmb   = (u16*)  nxt((size_t)B_MOL*HID*2);
    float* Gc    = (float*)nxt((size_t)B_MOL*HID*4);
    int*   flag  = (int*)  nxt(256);
    u16*   region= (u16*)  nxt((size_t)NTOT*2);
    // views into region
    u16* gxn    = region;
    u16* W1n    = region +   81920;
    u16* b1n    = region +   86720;
    u16* W2n    = region +   87680;
    u16* fgeN   = region + 1010240;
    u16* posN   = region + 1115200;
    u16* projWn = region + 1135680;
    u16* fuseWn = region + 2058240;
    u16* fusebn = region + 4515840;

    // ---- detect (+zero deg) + normalize (+b2f/projbf/zero bias-accum) ----
    k_detect<<<64,256,0,stream>>>((const u16*)d_in[0], flag, deg);
    NormSrcs ns;
    ns.p[0]=d_in[0]; ns.p[1]=d_in[6]; ns.p[2]=d_in[7]; ns.p[3]=d_in[8]; ns.p[4]=d_in[9];
    ns.p[5]=d_in[10]; ns.p[6]=d_in[11]; ns.p[7]=d_in[12]; ns.p[8]=d_in[13]; ns.p[9]=d_in[14]; ns.p[10]=d_in[15];
    k_normAll<<<(NTOT+255)/256,256,0,stream>>>(ns, region, b2f, projbf, tvb, flag);

    // ---- weight precompute ----
    k_transpose<<<dim3(HID/32, 2560/32), dim3(32,8), 0, stream>>>(fuseWn, fuseWT, 2560, HID);
    // z=0: Ub = Wc^T @ projW^T ; z=1: WglobT = Wd^T @ W2^T
    k_gemmS<<<dim3(15,15,2),256,0,stream>>>(fuseWT+640, fuseWT+1600, 2560, projWn, W2n, HID, Ub, WglobT);
    // WbigT = Ub @ W2^T
    k_gemmS<<<dim3(15,15,1),256,0,stream>>>(Ub, Ub, HID, W2n, W2n, HID, WbigT, WbigT);
    k_repackB<<<450,256,0,stream>>>(WbigT, WbigS);
    k_gemm<<<dim3(4,15),256,0,stream>>>(fgeN, 512, fuseWT, 2560, fgA, NFG, 512);
    k_gemm<<<dim3(1,15),256,0,stream>>>(posN, 128, fuseWT+512, 2560, pWbM, FMAXF, 128);
    k_vecmat3<<<dim3(15,16,3),256,0,stream>>>(b2f, projbf, b2f,
                                              projWn, fuseWn + 640*HID, fuseWn + 1600*HID,
                                              tvb, cC, gvec);
    k_vecmat<<<dim3(15,16),256,0,stream>>>(tvb, fuseWn + 640*HID, vb);
    k_addc<<<4,256,0,stream>>>(cC, gvec, fusebn, c0);

    // ---- graph path ----
    k_hist<<<256,256,0,stream>>>(edge_idx + E_EDGES, deg);
    k_scandinv<<<1,256,0,stream>>>(deg, off, cur, dinv);
    k_scatter<<<256,256,0,stream>>>(edge_idx, edge_idx + E_EDGES, dinv, cur, csr_s, csr_w);
    k_aggx<<<64,256,0,stream>>>(gxn, dinv, off, csr_s, csr_w, aggx);
    k_h1<<<7680,256,0,stream>>>(aggx, W1n, b1n, h1b);          // overwrites fuseWT/Ub (dead)
    k_p1<<<4096,256,0,stream>>>(h1b, dinv, off, csr_s, csr_w, P1b);
    k_gm<<<240,128,0,stream>>>(P1b, gmb);
    k_pr<<<2048,256,0,stream>>>(P1b, fg_idx, ptr, prb,         // overwrites h1b (dead)
                                evec, (u16*)d_out + OUT1, (float*)d_out + OUT1, flag);

    // Gc = gm @ (W2 Wd)
    k_gemm<<<dim3(4,15),256,0,stream>>>(gmb, HID, WglobT, HID, Gc, B_MOL, HID);
    // final
    k_gemmF<<<dim3(64,10),256,0,stream>>>(prb, WbigS, (float*)d_out, (u16*)d_out,
                                          fg_type, evec, fgA, pWbM, vb, c0, Gc, flag);
    (void)in_sizes; (void)n_in; (void)out_size; (void)ws_size;
}

// Round 6
// 320.500 us; speedup vs baseline: 3.6937x; 1.0065x over previous
//
#include <hip/hip_runtime.h>

typedef unsigned short u16;
typedef unsigned int u32;
typedef __attribute__((ext_vector_type(8))) short short8;
typedef __attribute__((ext_vector_type(4))) float f32x4;

#define N_NODES 16384
#define B_MOL   256
#define NPM     64
#define E_EDGES 65536
#define FMAXF   32
#define AMAXA   16
#define HID     960
#define NFG     205
#define BF_ROWS 8192
#define OUT1    7864320   // B*FMAX*HID
#define NTOT    4516800   // total normalized elements

__device__ __forceinline__ float bf2f(u16 u){ u32 x=((u32)u)<<16; float f; __builtin_memcpy(&f,&x,4); return f; }
__device__ __forceinline__ u16 f2bf(float f){ u32 x; __builtin_memcpy(&x,&f,4); x += 0x7FFFu + ((x>>16)&1u); return (u16)(x>>16); }

__device__ __forceinline__ void gload_lds16(const u16* g, u16* l){
    __builtin_amdgcn_global_load_lds(
        (const __attribute__((address_space(1))) void*)g,
        (__attribute__((address_space(3))) void*)l, 16, 0, 0);
}
// swizzled (fragment-region) address, in u16 units; col multiple of 8
__device__ __forceinline__ size_t swzA(int row, int col){
    return ((size_t)((row>>4)*30 + (col>>5)))*512 + (size_t)(((((col>>3)&3)*16) + (row&15))*8);
}

struct NormSrcs { const void* p[11]; };
// all 11 float tensors -> contiguous bf16 region; per-block local dtype flag (block0 publishes);
// also b2f/projbf fp32, zero tvb..gvec, zero deg
__global__ __launch_bounds__(256) void k_normAll(NormSrcs s, u16* __restrict__ region,
                                                 float* __restrict__ b2f, float* __restrict__ projbf,
                                                 float* __restrict__ z4, int* __restrict__ flag,
                                                 int* __restrict__ deg){
    __shared__ int cnt;
    int t = threadIdx.x;
    if (t==0) cnt = 0;
    __syncthreads();
    u16 pv = ((const u16*)s.p[0])[t*2];
    if (((pv>>7)&0xFF) >= 0xC0) atomicAdd(&cnt, 1);
    __syncthreads();
    int fl = (cnt > 16) ? 1 : 0;              // 1 => inputs are fp32
    int i = blockIdx.x*256 + t;
    if (blockIdx.x==0 && t==0) *flag = fl;
    if (i < N_NODES) deg[i] = 0;
    if (i < 4*HID) z4[i] = 0.f;
    if (i >= NTOT) return;
    int seg, off;
    if      (i <   81920){seg=0;  off=i;}
    else if (i <   86720){seg=1;  off=i-81920;}
    else if (i <   87680){seg=2;  off=i-86720;}
    else if (i < 1009280){seg=3;  off=i-87680;}
    else if (i < 1010240){seg=4;  off=i-1009280;}
    else if (i < 1115200){seg=5;  off=i-1010240;}
    else if (i < 1135680){seg=6;  off=i-1115200;}
    else if (i < 2057280){seg=7;  off=i-1135680;}
    else if (i < 2058240){seg=8;  off=i-2057280;}
    else if (i < 4515840){seg=9;  off=i-2058240;}
    else                 {seg=10; off=i-4515840;}
    const void* sp = s.p[seg];
    float fv; u16 uv;
    if (fl){ fv = ((const float*)sp)[off]; uv = f2bf(fv); }
    else   { uv = ((const u16*)sp)[off];  fv = bf2f(uv); }
    region[i] = uv;
    if (seg==4) b2f[off] = fv;
    if (seg==8) projbf[off] = fv;
}

// ---------------- graph prep ----------------
__global__ __launch_bounds__(256) void k_hist(const int* __restrict__ dst, int* __restrict__ deg){
    int e = blockIdx.x*256 + threadIdx.x; if (e < E_EDGES) atomicAdd(&deg[dst[e]], 1);
}
__global__ __launch_bounds__(1024) void k_scandinv(const int* __restrict__ deg, int* __restrict__ off,
                                                   int* __restrict__ cur, float* __restrict__ dinv){
    __shared__ int ps[1024];
    int t = threadIdx.x;
    const int chunk = N_NODES/1024; // 16
    int base0 = t*chunk;
    int s = 0;
    for (int i=0;i<chunk;i++) s += deg[base0+i];
    ps[t] = s; __syncthreads();
    for (int ofs=1; ofs<1024; ofs<<=1){
        int v = ps[t];
        int add = (t>=ofs) ? ps[t-ofs] : 0;
        __syncthreads();
        ps[t] = v + add;
        __syncthreads();
    }
    int run = (t==0) ? 0 : ps[t-1];
    for (int i=0;i<chunk;i++){
        int d = deg[base0+i];
        off[base0+i]=run; cur[base0+i]=run; run += d;
        dinv[base0+i] = rsqrtf(1.0f + (float)d);
    }
    if (t==1023) off[N_NODES] = run;
}
__global__ __launch_bounds__(256) void k_scatter(const int* __restrict__ src, const int* __restrict__ dst,
                                                 const float* __restrict__ dinv, int* __restrict__ cur,
                                                 int* __restrict__ csr_s, float* __restrict__ csr_w){
    int e = blockIdx.x*256 + threadIdx.x;
    if (e < E_EDGES){
        int s = src[e], d = dst[e];
        int p = atomicAdd(&cur[d], 1);
        csr_s[p] = s;
        csr_w[p] = dinv[s]*dinv[d];
    }
}
__global__ __launch_bounds__(256) void k_aggx(const u16* __restrict__ x, const float* __restrict__ dinv,
                                              const int* __restrict__ off, const int* __restrict__ csr_s,
                                              const float* __restrict__ csr_w, float* __restrict__ aggx){
    int n = blockIdx.x*256 + threadIdx.x;
    if (n >= N_NODES) return;
    float di = dinv[n], sw = di*di;
    float a[5];
    #pragma unroll
    for (int k=0;k<5;k++) a[k] = sw * bf2f(x[n*5+k]);
    int j0 = off[n], j1 = off[n+1];
    for (int j=j0;j<j1;j++){
        int s = csr_s[j]; float w = csr_w[j];
        #pragma unroll
        for (int k=0;k<5;k++) a[k] += w * bf2f(x[s*5+k]);
    }
    #pragma unroll
    for (int k=0;k<5;k++) aggx[n*5+k] = a[k];
}
__global__ __launch_bounds__(256) void k_h1(const float* __restrict__ aggx, const u16* __restrict__ W1,
                                            const u16* __restrict__ b1, u16* __restrict__ h1b){
    int id = blockIdx.x*256 + threadIdx.x;      // N*120 exact
    int n = id / 120; int c8 = (id - n*120)*8;
    float a[5];
    #pragma unroll
    for (int k=0;k<5;k++) a[k] = aggx[n*5+k];
    float r[8];
    short8 bb = *(const short8*)(b1 + c8);
    #pragma unroll
    for (int j=0;j<8;j++) r[j] = bf2f(((u16*)&bb)[j]);
    #pragma unroll
    for (int k=0;k<5;k++){
        short8 wv = *(const short8*)(W1 + k*HID + c8);
        #pragma unroll
        for (int j=0;j<8;j++) r[j] += a[k]*bf2f(((u16*)&wv)[j]);
    }
    short8 o;
    #pragma unroll
    for (int j=0;j<8;j++) ((u16*)&o)[j] = f2bf(fmaxf(r[j],0.f));
    *(short8*)(h1b + (size_t)n*HID + c8) = o;
}
// P1 = A_norm @ h1 : one WAVE per node, wave-uniform CSR loop
__global__ __launch_bounds__(256) void k_p1(const u16* __restrict__ h1b, const float* __restrict__ dinv,
                                            const int* __restrict__ off, const int* __restrict__ csr_s,
                                            const float* __restrict__ csr_w, u16* __restrict__ P1b){
    int wv = threadIdx.x>>6, lane = threadIdx.x&63;
    int n = blockIdx.x*4 + wv;
    int c = lane*16;
    bool act = lane < 60;
    float di = dinv[n], sw = di*di;
    float acc[16];
    if (act){
        short8 h0 = *(const short8*)(h1b + (size_t)n*HID + c);
        short8 h1v = *(const short8*)(h1b + (size_t)n*HID + c + 8);
        #pragma unroll
        for (int j=0;j<8;j++){ acc[j] = sw*bf2f(((u16*)&h0)[j]); acc[8+j] = sw*bf2f(((u16*)&h1v)[j]); }
    } else {
        #pragma unroll
        for (int j=0;j<16;j++) acc[j] = 0.f;
    }
    int j0 = off[n], j1 = off[n+1];
    for (int j=j0;j<j1;j++){
        int s = csr_s[j]; float w = csr_w[j];
        if (act){
            short8 v0 = *(const short8*)(h1b + (size_t)s*HID + c);
            short8 v1 = *(const short8*)(h1b + (size_t)s*HID + c + 8);
            #pragma unroll
            for (int j2=0;j2<8;j2++){ acc[j2] += w*bf2f(((u16*)&v0)[j2]); acc[8+j2] += w*bf2f(((u16*)&v1)[j2]); }
        }
    }
    if (act){
        short8 o0, o1;
        #pragma unroll
        for (int j=0;j<8;j++){ ((u16*)&o0)[j] = f2bf(acc[j]); ((u16*)&o1)[j] = f2bf(acc[8+j]); }
        *(short8*)(P1b + (size_t)n*HID + c) = o0;
        *(short8*)(P1b + (size_t)n*HID + c + 8) = o1;
    }
}
__global__ __launch_bounds__(128) void k_gm(const u16* __restrict__ P1b, u16* __restrict__ gmb){
    int id = blockIdx.x*128 + threadIdx.x;      // 256*120 exact
    int b = id / 120; int c8 = (id - b*120)*8;
    float s[8] = {0,0,0,0,0,0,0,0};
    for (int i=0;i<NPM;i++){
        short8 v = *(const short8*)(P1b + (size_t)(b*NPM+i)*HID + c8);
        #pragma unroll
        for (int j=0;j<8;j++) s[j] += bf2f(((u16*)&v)[j]);
    }
    const float inv = 1.0f/(float)NPM;
    short8 o;
    #pragma unroll
    for (int j=0;j<8;j++) ((u16*)&o)[j] = f2bf(s[j]*inv);
    *(short8*)(gmb + (size_t)b*HID + c8) = o;
}
// pr: one WAVE per (mol,fg); writes prb in SWIZZLED fragment layout
__global__ __launch_bounds__(256) void k_pr(const u16* __restrict__ P1b, const int* __restrict__ fgi,
                                            const int* __restrict__ ptr, u16* __restrict__ prb,
                                            float* __restrict__ evec, u16* __restrict__ maskb,
                                            float* __restrict__ maskf, const int* __restrict__ flag){
    int wv = threadIdx.x>>6, lane = threadIdx.x&63;
    int bf = blockIdx.x*4 + wv;
    int b = bf >> 5;
    int base = ptr[b];
    int c = lane*16;
    bool act = lane < 60;
    float acc[16];
    #pragma unroll
    for (int j=0;j<16;j++) acc[j] = 0.f;
    int cnt = 0;
    #pragma unroll
    for (int a=0;a<AMAXA;a++){
        int idx = fgi[bf*AMAXA + a];
        if (idx >= 0){
            cnt++;
            if (act){
                short8 v0 = *(const short8*)(P1b + (size_t)(base+idx)*HID + c);
                short8 v1 = *(const short8*)(P1b + (size_t)(base+idx)*HID + c + 8);
                #pragma unroll
                for (int j=0;j<8;j++){ acc[j] += bf2f(((u16*)&v0)[j]); acc[8+j] += bf2f(((u16*)&v1)[j]); }
            }
        }
    }
    float inv = (cnt>0) ? 1.0f/(float)cnt : 0.0f;
    if (act){
        short8 o0, o1;
        #pragma unroll
        for (int j=0;j<8;j++){ ((u16*)&o0)[j] = f2bf(acc[j]*inv); ((u16*)&o1)[j] = f2bf(acc[8+j]*inv); }
        *(short8*)(prb + swzA(bf, c)) = o0;
        *(short8*)(prb + swzA(bf, c+8)) = o1;
    }
    if (lane == 0){
        float e = (cnt>0) ? 1.0f : 0.0f;
        evec[bf] = e;
        if (*flag) maskf[bf] = e;
        else       maskb[bf] = f2bf(e);
    }
}
__global__ __launch_bounds__(256) void k_transpose(const u16* __restrict__ src, u16* __restrict__ dst, int R, int C){
    __shared__ __attribute__((aligned(16))) u16 t[32][33];
    int c0 = blockIdx.x*32, r0 = blockIdx.y*32;
    int tx = threadIdx.x, ty = threadIdx.y;   // 32 x 8
    #pragma unroll
    for (int i=0;i<4;i++) t[ty+i*8][tx] = src[(size_t)(r0+ty+i*8)*C + c0+tx];
    __syncthreads();
    #pragma unroll
    for (int i=0;i<4;i++) dst[(size_t)(c0+ty+i*8)*R + r0+tx] = t[tx][ty+i*8];
}
// WbigT row-major -> swizzled fragment layout
__global__ __launch_bounds__(256) void k_repackB(const u16* __restrict__ src, u16* __restrict__ dst){
    int id = blockIdx.x*256 + threadIdx.x;   // 960*120 exact
    int n = id / 120; int k8 = (id - n*120)*8;
    short8 v = *(const short8*)(src + (size_t)n*HID + k8);
    *(short8*)(dst + swzA(n, k8)) = v;
}
// split-K vec-mat (+= into pre-zeroed out), grid (15,16)
__device__ __forceinline__ void vecmat_body(const float* v, const u16* M, float* out){
    __shared__ float part[4][64];
    int tid = threadIdx.x;
    int cl = tid & 63;
    int c = blockIdx.x*64 + cl;
    int kg = tid >> 6;
    int k0 = blockIdx.y*60 + kg*15;
    float s = 0.f;
    #pragma unroll
    for (int i=0;i<15;i++){
        int k = k0 + i;
        s += v[k]*bf2f(M[(size_t)k*HID + c]);
    }
    part[kg][cl] = s;
    __syncthreads();
    if (kg==0){
        float r = part[0][cl] + part[1][cl] + part[2][cl] + part[3][cl];
        atomicAdd(&out[c], r);
    }
}
__global__ __launch_bounds__(256) void k_vecmat(const float* __restrict__ v, const u16* __restrict__ M,
                                                float* __restrict__ out){
    vecmat_body(v, M, out);
}
__global__ __launch_bounds__(256) void k_vecmat3(const float* s0, const float* s1, const float* s2,
                                                 const u16* M0, const u16* M1, const u16* M2,
                                                 float* o0, float* o1, float* o2){
    const float* v; const u16* M; float* out;
    if (blockIdx.z==0){v=s0;M=M0;out=o0;}
    else if (blockIdx.z==1){v=s1;M=M1;out=o1;}
    else {v=s2;M=M2;out=o2;}
    vecmat_body(v, M, out);
}
__global__ __launch_bounds__(256) void k_addc(const float* __restrict__ a, const float* __restrict__ b,
                                              const u16* __restrict__ fb, float* __restrict__ out){
    int c = blockIdx.x*256 + threadIdx.x; if (c<HID) out[c] = a[c] + b[c] + bf2f(fb[c]);
}

// ---------------- generic 64x64 GEMM body, fp32 out ----------------
__device__ __forceinline__ void gemm64_body(
    const u16* __restrict__ A, int lda, const u16* __restrict__ Bt, int ldb,
    float* __restrict__ C, int M, int K)
{
    __shared__ __attribute__((aligned(16))) u16 As[64*40];
    __shared__ __attribute__((aligned(16))) u16 Bs[64*40];
    const int tid = threadIdx.x;
    const int wave = tid>>6, lane = tid&63;
    const int wm = wave>>1, wn = wave&1;
    const int q = lane>>4, l16 = lane&15;
    const int m0 = blockIdx.x*64, n0 = blockIdx.y*64;
    const int sm = tid>>2, sk = (tid&3)*8;

    f32x4 acc00={0,0,0,0}, acc01={0,0,0,0}, acc10={0,0,0,0}, acc11={0,0,0,0};
    const bool aOk = (m0+sm) < M;
    const u16* Ap = A + (size_t)(m0+sm)*lda + sk;
    const u16* Bp = Bt + (size_t)(n0+sm)*ldb + sk;

    for (int k0=0; k0<K; k0+=32){
        short8 av = {0,0,0,0,0,0,0,0};
        if (aOk) av = *(const short8*)(Ap + k0);
        short8 bv = *(const short8*)(Bp + k0);
        *(short8*)(As + sm*40 + sk) = av;
        *(short8*)(Bs + sm*40 + sk) = bv;
        __syncthreads();
        short8 a0 = *(const short8*)(As + (wm*32      + l16)*40 + q*8);
        short8 a1 = *(const short8*)(As + (wm*32 + 16 + l16)*40 + q*8);
        short8 b0 = *(const short8*)(Bs + (wn*32      + l16)*40 + q*8);
        short8 b1 = *(const short8*)(Bs + (wn*32 + 16 + l16)*40 + q*8);
        acc00 = __builtin_amdgcn_mfma_f32_16x16x32_bf16(a0,b0,acc00,0,0,0);
        acc01 = __builtin_amdgcn_mfma_f32_16x16x32_bf16(a0,b1,acc01,0,0,0);
        acc10 = __builtin_amdgcn_mfma_f32_16x16x32_bf16(a1,b0,acc10,0,0,0);
        acc11 = __builtin_amdgcn_mfma_f32_16x16x32_bf16(a1,b1,acc11,0,0,0);
        __syncthreads();
    }
    #pragma unroll
    for (int i=0;i<2;i++){
        int rowb = m0 + wm*32 + i*16 + q*4;
        #pragma unroll
        for (int j=0;j<2;j++){
            int col = n0 + wn*32 + j*16 + l16;
            f32x4 av = (i==0) ? ((j==0)?acc00:acc01) : ((j==0)?acc10:acc11);
            #pragma unroll
            for (int r=0;r<4;r++){
                int row = rowb + r;
                if (row < M) C[(size_t)row*HID + col] = av[r];
            }
        }
    }
}
__global__ __launch_bounds__(256) void k_gemm(
    const u16* __restrict__ A, int lda, const u16* __restrict__ Bt, int ldb,
    float* __restrict__ C, int M, int K){
    gemm64_body(A, lda, Bt, ldb, C, M, K);
}
// z-batched pair of small fp32-out GEMMs
__global__ __launch_bounds__(256) void k_gemmB(
    const u16* A0, int lda0, const u16* B0, int ldb0, float* C0, int M0, int K0,
    const u16* A1, int lda1, const u16* B1, int ldb1, float* C1, int M1, int K1)
{
    if (blockIdx.z == 0) gemm64_body(A0, lda0, B0, ldb0, C0, M0, K0);
    else { if ((int)blockIdx.x*64 >= M1) return; gemm64_body(A1, lda1, B1, ldb1, C1, M1, K1); }
}

// ---------------- square 960 GEMM, bf16 out, z-batched pair ----------------
__global__ __launch_bounds__(256) void k_gemmS(
    const u16* A0, const u16* A1, int lda,
    const u16* B0, const u16* B1, int ldb,
    u16* C0, u16* C1)
{
    const u16* A  = blockIdx.z ? A1 : A0;
    const u16* Bt = blockIdx.z ? B1 : B0;
    u16* C        = blockIdx.z ? C1 : C0;
    __shared__ __attribute__((aligned(16))) u16 As[64*40];
    __shared__ __attribute__((aligned(16))) u16 Bs[64*40];
    const int tid = threadIdx.x;
    const int wave = tid>>6, lane = tid&63;
    const int wm = wave>>1, wn = wave&1;
    const int q = lane>>4, l16 = lane&15;
    const int m0 = blockIdx.x*64, n0 = blockIdx.y*64;
    const int sm = tid>>2, sk = (tid&3)*8;

    f32x4 acc00={0,0,0,0}, acc01={0,0,0,0}, acc10={0,0,0,0}, acc11={0,0,0,0};
    const u16* Ap = A + (size_t)(m0+sm)*lda + sk;
    const u16* Bp = Bt + (size_t)(n0+sm)*ldb + sk;

    for (int k0=0; k0<HID; k0+=32){
        short8 av = *(const short8*)(Ap + k0);
        short8 bv = *(const short8*)(Bp + k0);
        *(short8*)(As + sm*40 + sk) = av;
        *(short8*)(Bs + sm*40 + sk) = bv;
        __syncthreads();
        short8 a0 = *(const short8*)(As + (wm*32      + l16)*40 + q*8);
        short8 a1 = *(const short8*)(As + (wm*32 + 16 + l16)*40 + q*8);
        short8 b0 = *(const short8*)(Bs + (wn*32      + l16)*40 + q*8);
        short8 b1 = *(const short8*)(Bs + (wn*32 + 16 + l16)*40 + q*8);
        acc00 = __builtin_amdgcn_mfma_f32_16x16x32_bf16(a0,b0,acc00,0,0,0);
        acc01 = __builtin_amdgcn_mfma_f32_16x16x32_bf16(a0,b1,acc01,0,0,0);
        acc10 = __builtin_amdgcn_mfma_f32_16x16x32_bf16(a1,b0,acc10,0,0,0);
        acc11 = __builtin_amdgcn_mfma_f32_16x16x32_bf16(a1,b1,acc11,0,0,0);
        __syncthreads();
    }
    #pragma unroll
    for (int i=0;i<2;i++){
        int rowb = m0 + wm*32 + i*16 + q*4;
        #pragma unroll
        for (int j=0;j<2;j++){
            int col = n0 + wn*32 + j*16 + l16;
            f32x4 av = (i==0) ? ((j==0)?acc00:acc01) : ((j==0)?acc10:acc11);
            #pragma unroll
            for (int r=0;r<4;r++) C[(size_t)(rowb+r)*HID + col] = f2bf(av[r]);
        }
    }
}

// ------- final GEMM: out[8192,960] = prb @ WbigS^T + epilogue -------
// BM=64, BN=96, dbuf LDS, loads issued after barrier -> overlap with MFMA; grid 128x10 = 5 blocks/CU exact
__global__ __launch_bounds__(256) void k_gemmF(
    const u16* __restrict__ A, const u16* __restrict__ Bt,
    float* __restrict__ Cf, u16* __restrict__ Cb,
    const int* __restrict__ fg_type, const float* __restrict__ evec,
    const float* __restrict__ fgA, const float* __restrict__ pWbM,
    const float* __restrict__ vb, const float* __restrict__ c0,
    const float* __restrict__ Gc, const int* __restrict__ flag)
{
    __shared__ __attribute__((aligned(16))) u16 S[2][10*512];   // regions: A 0..3, B 4..9
    const int tid = threadIdx.x;
    const int wave = tid>>6, lane = tid&63;
    const int q = lane>>4, l16 = lane&15;
    const int m0 = blockIdx.x*64, n0 = blockIdx.y*96;
    const int R0 = blockIdx.x*4, N0 = blockIdx.y*6;

    f32x4 acc[6];
    #pragma unroll
    for (int j=0;j<6;j++) acc[j] = (f32x4){0,0,0,0};

    const u16* gA  = A  + ((size_t)(R0 + wave    )*30)*512 + lane*8;
    const u16* gB0 = Bt + ((size_t)(N0 + wave    )*30)*512 + lane*8;
    const u16* gB1 = Bt + ((size_t)(N0 + 4 + wave)*30)*512 + lane*8;  // only wave<2

    // prefetch kc=0 into buffer 0
    gload_lds16(gA,  &S[0][wave*512]);
    gload_lds16(gB0, &S[0][(4+wave)*512]);
    if (wave < 2) gload_lds16(gB1, &S[0][(8+wave)*512]);

    int buf = 0;
    for (int kc=0; kc<30; kc++){
        __syncthreads();                       // vmcnt(0) here drains loads for THIS buf (issued last iter)
        if (kc < 29){                          // issue next tile into other buf; overlaps ds_read+MFMA below
            int kn = (kc+1)*512;
            gload_lds16(gA  + kn, &S[buf^1][wave*512]);
            gload_lds16(gB0 + kn, &S[buf^1][(4+wave)*512]);
            if (wave < 2) gload_lds16(gB1 + kn, &S[buf^1][(8+wave)*512]);
        }
        short8 af = *(const short8*)(&S[buf][wave*512 + lane*8]);
        short8 bfr[6];
        #pragma unroll
        for (int j=0;j<6;j++) bfr[j] = *(const short8*)(&S[buf][(4+j)*512 + lane*8]);
        #pragma unroll
        for (int j=0;j<6;j++)
            acc[j] = __builtin_amdgcn_mfma_f32_16x16x32_bf16(af, bfr[j], acc[j], 0,0,0);
        buf ^= 1;
    }

    const int isf = *flag;
    int rowb = m0 + wave*16 + q*4;
    #pragma unroll
    for (int r=0;r<4;r++){
        int row = rowb + r;
        int bb = row>>5, ff = row&31;
        int ty = fg_type[row];
        float e = evec[row];
        #pragma unroll
        for (int j=0;j<6;j++){
            int col = n0 + j*16 + l16;
            float v = acc[j][r]
                    + fgA[ty*HID+col] + pWbM[ff*HID+col]
                    + e*vb[col] + c0[col] + Gc[bb*HID+col];
            if (isf) Cf[(size_t)row*HID + col] = v;
            else     Cb[(size_t)row*HID + col] = f2bf(v);
        }
    }
}

extern "C" void kernel_launch(void* const* d_in, const int* in_sizes, int n_in,
                              void* d_out, int out_size, void* d_ws, size_t ws_size,
                              hipStream_t stream) {
    const int* edge_idx  = (const int*)d_in[1];
    const int* ptr       = (const int*)d_in[3];
    const int* fg_type   = (const int*)d_in[4];
    const int* fg_idx    = (const int*)d_in[5];

    // ---- workspace layout ----
    char* w = (char*)d_ws;
    auto nxt = [&](size_t b)->char*{ char* p = w; w += (b + 255) & ~(size_t)255; return p; };
    u16* big0   = (u16*)nxt((size_t)N_NODES*HID*2);       // fuseWT+Ub -> h1b -> prb(swizzled)
    u16* fuseWT = big0;
    u16* Ub     = big0 + (size_t)HID*2560;
    u16* h1b    = big0;
    u16* prb    = big0;
    u16* P1b    = (u16*)nxt((size_t)N_NODES*HID*2);
    u16*  WbigT  = (u16*) nxt((size_t)HID*HID*2);
    u16*  WbigS  = (u16*) nxt((size_t)HID*HID*2);
    u16*  WglobT = (u16*) nxt((size_t)HID*HID*2);
    float* fgA   = (float*)nxt((size_t)NFG*HID*4);
    float* pWbM  = (float*)nxt((size_t)FMAXF*HID*4);
    float* b2f   = (float*)nxt(HID*4);
    float* projbf= (float*)nxt(HID*4);
    float* tvb   = (float*)nxt(HID*4);   // tvb, vb, cC, gvec contiguous
    float* vb    = (float*)nxt(HID*4);
    float* cC    = (float*)nxt(HID*4);
    float* gvec  = (float*)nxt(HID*4);
    float* c0    = (float*)nxt(HID*4);
    int*   deg   = (int*)  nxt(N_NODES*4);
    float* dinv  = (float*)nxt(N_NODES*4);
    int*   off   = (int*)  nxt((N_NODES+1)*4);
    int*   cur   = (int*)  nxt(N_NODES*4);
    int*   csr_s = (int*)  nxt(E_EDGES*4);
    float* csr_w = (float*)nxt(E_EDGES*4);
    float* aggx  = (float*)nxt((size_t)N_NODES*5*4);
    float* evec  = (float*)nxt(BF_ROWS*4);
    u16*   gmb   = (u16*)  nxt((size_t)B_MOL*HID*2);
    float* Gc    = (float*)nxt((size_t)B_MOL*HID*4);
    int*   flag  = (int*)  nxt(256);
    u16*   region= (u16*)  nxt((size_t)NTOT*2);
    // views into region
    u16* gxn    = region;
    u16* W1n    = region +   81920;
    u16* b1n    = region +   86720;
    u16* W2n    = region +   87680;
    u16* fgeN   = region + 1010240;
    u16* posN   = region + 1115200;
    u16* projWn = region + 1135680;
    u16* fuseWn = region + 2058240;
    u16* fusebn = region + 4515840;

    // ---- normalize (+local dtype flag, +b2f/projbf, +zero deg & bias-accum) ----
    NormSrcs ns;
    ns.p[0]=d_in[0]; ns.p[1]=d_in[6]; ns.p[2]=d_in[7]; ns.p[3]=d_in[8]; ns.p[4]=d_in[9];
    ns.p[5]=d_in[10]; ns.p[6]=d_in[11]; ns.p[7]=d_in[12]; ns.p[8]=d_in[13]; ns.p[9]=d_in[14]; ns.p[10]=d_in[15];
    k_normAll<<<(NTOT+255)/256,256,0,stream>>>(ns, region, b2f, projbf, tvb, flag, deg);

    // ---- weight precompute ----
    k_transpose<<<dim3(HID/32, 2560/32), dim3(32,8), 0, stream>>>(fuseWn, fuseWT, 2560, HID);
    // z=0: Ub = Wc^T @ projW^T ; z=1: WglobT = Wd^T @ W2^T
    k_gemmS<<<dim3(15,15,2),256,0,stream>>>(fuseWT+640, fuseWT+1600, 2560, projWn, W2n, HID, Ub, WglobT);
    // WbigT = Ub @ W2^T
    k_gemmS<<<dim3(15,15,1),256,0,stream>>>(Ub, Ub, HID, W2n, W2n, HID, WbigT, WbigT);
    k_repackB<<<450,256,0,stream>>>(WbigT, WbigS);
    // z=0: fgA = fg_embed @ Wa ; z=1: pWbM = pos_embed[:32] @ Wb
    k_gemmB<<<dim3(4,15,2),256,0,stream>>>(fgeN, 512, fuseWT, 2560, fgA, NFG, 512,
                                           posN, 128, fuseWT+512, 2560, pWbM, FMAXF, 128);
    k_vecmat3<<<dim3(15,16,3),256,0,stream>>>(b2f, projbf, b2f,
                                              projWn, fuseWn + 640*HID, fuseWn + 1600*HID,
                                              tvb, cC, gvec);
    k_vecmat<<<dim3(15,16),256,0,stream>>>(tvb, fuseWn + 640*HID, vb);
    k_addc<<<4,256,0,stream>>>(cC, gvec, fusebn, c0);

    // ---- graph path ----
    k_hist<<<256,256,0,stream>>>(edge_idx + E_EDGES, deg);
    k_scandinv<<<1,1024,0,stream>>>(deg, off, cur, dinv);
    k_scatter<<<256,256,0,stream>>>(edge_idx, edge_idx + E_EDGES, dinv, cur, csr_s, csr_w);
    k_aggx<<<64,256,0,stream>>>(gxn, dinv, off, csr_s, csr_w, aggx);
    k_h1<<<7680,256,0,stream>>>(aggx, W1n, b1n, h1b);          // overwrites fuseWT/Ub (dead)
    k_p1<<<4096,256,0,stream>>>(h1b, dinv, off, csr_s, csr_w, P1b);
    k_gm<<<240,128,0,stream>>>(P1b, gmb);
    k_pr<<<2048,256,0,stream>>>(P1b, fg_idx, ptr, prb,         // overwrites h1b (dead)
                                evec, (u16*)d_out + OUT1, (float*)d_out + OUT1, flag);

    // Gc = gm @ (W2 Wd)
    k_gemm<<<dim3(4,15),256,0,stream>>>(gmb, HID, WglobT, HID, Gc, B_MOL, HID);
    // final
    k_gemmF<<<dim3(128,10),256,0,stream>>>(prb, WbigS, (float*)d_out, (u16*)d_out,
                                           fg_type, evec, fgA, pWbM, vb, c0, Gc, flag);
    (void)in_sizes; (void)n_in; (void)out_size; (void)ws_size;
}

// Round 7
// 291.122 us; speedup vs baseline: 4.0665x; 1.1009x over previous
//
#include <hip/hip_runtime.h>

typedef unsigned short u16;
typedef unsigned int u32;
typedef __attribute__((ext_vector_type(8))) short short8;
typedef __attribute__((ext_vector_type(4))) float f32x4;

#define N_NODES 16384
#define B_MOL   256
#define NPM     64
#define E_EDGES 65536
#define FMAXF   32
#define AMAXA   16
#define HID     960
#define NFG     205
#define BF_ROWS 8192
#define OUT1    7864320   // B*FMAX*HID
#define NTOT    4516800   // total normalized elements

__device__ __forceinline__ float bf2f(u16 u){ u32 x=((u32)u)<<16; float f; __builtin_memcpy(&f,&x,4); return f; }
__device__ __forceinline__ u16 f2bf(float f){ u32 x; __builtin_memcpy(&x,&f,4); x += 0x7FFFu + ((x>>16)&1u); return (u16)(x>>16); }

__device__ __forceinline__ void gload_lds16(const u16* g, u16* l){
    __builtin_amdgcn_global_load_lds(
        (const __attribute__((address_space(1))) void*)g,
        (__attribute__((address_space(3))) void*)l, 16, 0, 0);
}
// swizzled fragment-region address (16-row x 32-col regions of a 960-col matrix)
__device__ __forceinline__ size_t swzA(int row, int col){      // col multiple of 8, u16 units
    return ((size_t)((row>>4)*30 + (col>>5)))*512 + (size_t)(((((col>>3)&3)*16) + (row&15))*8);
}
__device__ __forceinline__ size_t swzE(int row, int col){      // element-granular
    return ((size_t)((row>>4)*30 + (col>>5)))*512 + (size_t)((((col>>3)&3)*16 + (row&15))*8 + (col&7));
}

struct NormSrcs { const void* p[11]; };
// all 11 float tensors -> contiguous bf16 region; per-block dtype flag; b2f/projbf fp32; zero deg + bias-accum
__global__ __launch_bounds__(256) void k_normAll(NormSrcs s, u16* __restrict__ region,
                                                 float* __restrict__ b2f, float* __restrict__ projbf,
                                                 float* __restrict__ z4, int* __restrict__ flag,
                                                 int* __restrict__ deg){
    __shared__ int cnt;
    int t = threadIdx.x;
    if (t==0) cnt = 0;
    __syncthreads();
    u16 pv = ((const u16*)s.p[0])[t*2];
    if (((pv>>7)&0xFF) >= 0xC0) atomicAdd(&cnt, 1);
    __syncthreads();
    int fl = (cnt > 16) ? 1 : 0;              // 1 => inputs are fp32
    int i = blockIdx.x*256 + t;
    if (blockIdx.x==0 && t==0) *flag = fl;
    if (i < N_NODES) deg[i] = 0;
    if (i < 4*HID) z4[i] = 0.f;
    if (i >= NTOT) return;
    int seg, off;
    if      (i <   81920){seg=0;  off=i;}
    else if (i <   86720){seg=1;  off=i-81920;}
    else if (i <   87680){seg=2;  off=i-86720;}
    else if (i < 1009280){seg=3;  off=i-87680;}
    else if (i < 1010240){seg=4;  off=i-1009280;}
    else if (i < 1115200){seg=5;  off=i-1010240;}
    else if (i < 1135680){seg=6;  off=i-1115200;}
    else if (i < 2057280){seg=7;  off=i-1135680;}
    else if (i < 2058240){seg=8;  off=i-2057280;}
    else if (i < 4515840){seg=9;  off=i-2058240;}
    else                 {seg=10; off=i-4515840;}
    const void* sp = s.p[seg];
    float fv; u16 uv;
    if (fl){ fv = ((const float*)sp)[off]; uv = f2bf(fv); }
    else   { uv = ((const u16*)sp)[off];  fv = bf2f(uv); }
    region[i] = uv;
    if (seg==4) b2f[off] = fv;
    if (seg==8) projbf[off] = fv;
}

// ================= device bodies (parameterized by block coords + smem) =================

// square-960 bf16 GEMM: C = A @ Bt^T (bf16 out; optional swizzled store)
__device__ __forceinline__ void gemm_sq(int bx, int by, const u16* __restrict__ A, int lda,
                                        const u16* __restrict__ Bt, int ldb,
                                        u16* __restrict__ C, int swz, char* smem)
{
    u16* As = (u16*)smem;            // 64*40
    u16* Bs = (u16*)smem + 64*40;
    const int tid = threadIdx.x;
    const int wave = tid>>6, lane = tid&63;
    const int wm = wave>>1, wn = wave&1;
    const int q = lane>>4, l16 = lane&15;
    const int m0 = bx*64, n0 = by*64;
    const int sm = tid>>2, sk = (tid&3)*8;
    f32x4 acc00={0,0,0,0}, acc01={0,0,0,0}, acc10={0,0,0,0}, acc11={0,0,0,0};
    const u16* Ap = A + (size_t)(m0+sm)*lda + sk;
    const u16* Bp = Bt + (size_t)(n0+sm)*ldb + sk;
    for (int k0=0; k0<HID; k0+=32){
        short8 av = *(const short8*)(Ap + k0);
        short8 bv = *(const short8*)(Bp + k0);
        *(short8*)(As + sm*40 + sk) = av;
        *(short8*)(Bs + sm*40 + sk) = bv;
        __syncthreads();
        short8 a0 = *(const short8*)(As + (wm*32      + l16)*40 + q*8);
        short8 a1 = *(const short8*)(As + (wm*32 + 16 + l16)*40 + q*8);
        short8 b0 = *(const short8*)(Bs + (wn*32      + l16)*40 + q*8);
        short8 b1 = *(const short8*)(Bs + (wn*32 + 16 + l16)*40 + q*8);
        acc00 = __builtin_amdgcn_mfma_f32_16x16x32_bf16(a0,b0,acc00,0,0,0);
        acc01 = __builtin_amdgcn_mfma_f32_16x16x32_bf16(a0,b1,acc01,0,0,0);
        acc10 = __builtin_amdgcn_mfma_f32_16x16x32_bf16(a1,b0,acc10,0,0,0);
        acc11 = __builtin_amdgcn_mfma_f32_16x16x32_bf16(a1,b1,acc11,0,0,0);
        __syncthreads();
    }
    #pragma unroll
    for (int i=0;i<2;i++){
        int rowb = m0 + wm*32 + i*16 + q*4;
        #pragma unroll
        for (int j=0;j<2;j++){
            int col = n0 + wn*32 + j*16 + l16;
            f32x4 av = (i==0) ? ((j==0)?acc00:acc01) : ((j==0)?acc10:acc11);
            #pragma unroll
            for (int r=0;r<4;r++){
                int row = rowb + r;
                u16 o = f2bf(av[r]);
                if (swz) C[swzE(row,col)] = o;
                else     C[(size_t)row*HID + col] = o;
            }
        }
    }
}
// 64x64-tile GEMM, fp32 out, row guard, optional column-vector add
__device__ __forceinline__ void gemm64f(int bx, int by, const u16* __restrict__ A, int lda,
                                        const u16* __restrict__ Bt, int ldb,
                                        float* __restrict__ C, int M, int K,
                                        const float* __restrict__ addv, char* smem)
{
    u16* As = (u16*)smem;
    u16* Bs = (u16*)smem + 64*40;
    const int tid = threadIdx.x;
    const int wave = tid>>6, lane = tid&63;
    const int wm = wave>>1, wn = wave&1;
    const int q = lane>>4, l16 = lane&15;
    const int m0 = bx*64, n0 = by*64;
    const int sm = tid>>2, sk = (tid&3)*8;
    f32x4 acc00={0,0,0,0}, acc01={0,0,0,0}, acc10={0,0,0,0}, acc11={0,0,0,0};
    const bool aOk = (m0+sm) < M;
    const u16* Ap = A + (size_t)(m0+sm)*lda + sk;
    const u16* Bp = Bt + (size_t)(n0+sm)*ldb + sk;
    for (int k0=0; k0<K; k0+=32){
        short8 av = {0,0,0,0,0,0,0,0};
        if (aOk) av = *(const short8*)(Ap + k0);
        short8 bv = *(const short8*)(Bp + k0);
        *(short8*)(As + sm*40 + sk) = av;
        *(short8*)(Bs + sm*40 + sk) = bv;
        __syncthreads();
        short8 a0 = *(const short8*)(As + (wm*32      + l16)*40 + q*8);
        short8 a1 = *(const short8*)(As + (wm*32 + 16 + l16)*40 + q*8);
        short8 b0 = *(const short8*)(Bs + (wn*32      + l16)*40 + q*8);
        short8 b1 = *(const short8*)(Bs + (wn*32 + 16 + l16)*40 + q*8);
        acc00 = __builtin_amdgcn_mfma_f32_16x16x32_bf16(a0,b0,acc00,0,0,0);
        acc01 = __builtin_amdgcn_mfma_f32_16x16x32_bf16(a0,b1,acc01,0,0,0);
        acc10 = __builtin_amdgcn_mfma_f32_16x16x32_bf16(a1,b0,acc10,0,0,0);
        acc11 = __builtin_amdgcn_mfma_f32_16x16x32_bf16(a1,b1,acc11,0,0,0);
        __syncthreads();
    }
    #pragma unroll
    for (int i=0;i<2;i++){
        int rowb = m0 + wm*32 + i*16 + q*4;
        #pragma unroll
        for (int j=0;j<2;j++){
            int col = n0 + wn*32 + j*16 + l16;
            f32x4 av = (i==0) ? ((j==0)?acc00:acc01) : ((j==0)?acc10:acc11);
            float add = addv ? addv[col] : 0.f;
            #pragma unroll
            for (int r=0;r<4;r++){
                int row = rowb + r;
                if (row < M) C[(size_t)row*HID + col] = av[r] + add;
            }
        }
    }
}
// bf16 transpose tile (src[R=2560 rows? generic], here fuseW [2560,960] -> fuseWT [960,2560])
__device__ __forceinline__ void transpose_tile(int bx, int by, const u16* __restrict__ src,
                                               u16* __restrict__ dst, int R, int C, char* smem)
{
    u16 (*tl)[33] = (u16(*)[33])smem;
    int c0 = bx*32, r0 = by*32;
    int tx = threadIdx.x & 31, ty = threadIdx.x >> 5;   // 32x8
    #pragma unroll
    for (int i=0;i<4;i++) tl[ty+i*8][tx] = src[(size_t)(r0+ty+i*8)*C + c0+tx];
    __syncthreads();
    #pragma unroll
    for (int i=0;i<4;i++) dst[(size_t)(c0+ty+i*8)*R + r0+tx] = tl[tx][ty+i*8];
}
// split-K vec-mat, += into pre-zeroed out
__device__ __forceinline__ void vecmat_body(int bx, int by, const float* __restrict__ v,
                                            const u16* __restrict__ M, float* __restrict__ out, char* smem)
{
    float (*part)[64] = (float(*)[64])smem;
    int tid = threadIdx.x;
    int cl = tid & 63;
    int c = bx*64 + cl;
    int kg = tid >> 6;
    int k0 = by*60 + kg*15;
    float s = 0.f;
    #pragma unroll
    for (int i=0;i<15;i++) s += v[k0+i]*bf2f(M[(size_t)(k0+i)*HID + c]);
    part[kg][cl] = s;
    __syncthreads();
    if (kg==0) atomicAdd(&out[c], part[0][cl]+part[1][cl]+part[2][cl]+part[3][cl]);
}
// 256-thread scan + dinv
__device__ __forceinline__ void scandinv_body(const int* __restrict__ deg, int* __restrict__ off,
                                              int* __restrict__ cur, float* __restrict__ dinv, char* smem)
{
    int* ps = (int*)smem;
    int t = threadIdx.x;
    const int chunk = N_NODES/256; // 64
    int base0 = t*chunk;
    int s = 0;
    for (int i=0;i<chunk;i++) s += deg[base0+i];
    ps[t] = s; __syncthreads();
    for (int ofs=1; ofs<256; ofs<<=1){
        int v = ps[t];
        int add = (t>=ofs) ? ps[t-ofs] : 0;
        __syncthreads();
        ps[t] = v + add;
        __syncthreads();
    }
    int run = (t==0) ? 0 : ps[t-1];
    for (int i=0;i<chunk;i++){
        int d = deg[base0+i];
        off[base0+i]=run; cur[base0+i]=run; run += d;
        dinv[base0+i] = rsqrtf(1.0f + (float)d);
    }
    if (t==255) off[N_NODES] = run;
}

// ================= fused selector kernels =================
// L1: fuseW transpose (2400 blocks) + hist (256)
__global__ __launch_bounds__(256) void k_L1(const u16* __restrict__ fuseWn, u16* __restrict__ fuseWT,
                                            const int* __restrict__ dst, int* __restrict__ deg){
    __shared__ __attribute__((aligned(16))) char smem[2112];
    int b = blockIdx.x;
    if (b < 2400){
        transpose_tile(b%30, b/30, fuseWn, fuseWT, 2560, HID, smem);
    } else {
        int e = (b-2400)*256 + threadIdx.x;
        if (e < E_EDGES) atomicAdd(&deg[dst[e]], 1);
    }
}
// L2: gemmS pair (Ub, WglobT) (450) + scandinv (1)
__global__ __launch_bounds__(256) void k_L2(const u16* fuseWT, const u16* projWn, const u16* W2n,
                                            u16* Ub, u16* WglobT,
                                            const int* deg, int* off, int* cur, float* dinv){
    __shared__ __attribute__((aligned(16))) char smem[10240];
    int b = blockIdx.x;
    if (b < 450){
        int z = b/225, r = b%225;
        if (z==0) gemm_sq(r%15, r/15, fuseWT+640, 2560, projWn, HID, Ub, 0, smem);
        else      gemm_sq(r%15, r/15, fuseWT+1600, 2560, W2n, HID, WglobT, 0, smem);
    } else {
        scandinv_body(deg, off, cur, dinv, smem);
    }
}
// L3: WbigS = (Ub @ W2^T) swizzled (225) + gemmB fgA/pWbM (75) + scatter (256)
__global__ __launch_bounds__(256) void k_L3(const u16* Ub, const u16* W2n, u16* WbigS,
                                            const u16* fgeN, const u16* posN, const u16* fuseWT,
                                            float* fgA, float* pWbM,
                                            const int* src, const int* dst, const float* dinv,
                                            int* cur, int* csr_s, float* csr_w){
    __shared__ __attribute__((aligned(16))) char smem[10240];
    int b = blockIdx.x;
    if (b < 225){
        gemm_sq(b%15, b/15, Ub, HID, W2n, HID, WbigS, 1, smem);
    } else if (b < 300){
        int bb = b-225;
        if (bb < 60) gemm64f(bb%4, bb/4, fgeN, 512, fuseWT, 2560, fgA, NFG, 512, nullptr, smem);
        else         gemm64f(0, bb-60, posN, 128, fuseWT+512, 2560, pWbM, FMAXF, 128, nullptr, smem);
    } else {
        int e = (b-300)*256 + threadIdx.x;
        if (e < E_EDGES){
            int s = src[e], d = dst[e];
            int p = atomicAdd(&cur[d], 1);
            csr_s[p] = s;
            csr_w[p] = dinv[s]*dinv[d];
        }
    }
}
// L4: fused aggx+h1 (8192 blocks, 2 nodes each) + vecmat3 (720)
__global__ __launch_bounds__(256) void k_L4(const u16* __restrict__ gxn, const float* __restrict__ dinv,
                                            const int* __restrict__ off, const int* __restrict__ csr_s,
                                            const float* __restrict__ csr_w,
                                            const u16* __restrict__ W1, const u16* __restrict__ b1,
                                            u16* __restrict__ h1b,
                                            const float* b2f, const float* projbf, const u16* fuseWn,
                                            const u16* projWn, float* tvb, float* cC, float* gvec){
    __shared__ __attribute__((aligned(16))) char smem[1024];
    int b = blockIdx.x;
    if (b < 8192){
        float* a2 = (float*)smem;     // [2][8]
        int t = threadIdx.x;
        int h = t>>7, tl = t&127;
        int n = b*2 + h;
        if (tl < 5){
            int k = tl;
            float di = dinv[n], sw = di*di;
            float a = sw * bf2f(gxn[n*5+k]);
            int j0 = off[n], j1 = off[n+1];
            for (int j=j0;j<j1;j++) a += csr_w[j]*bf2f(gxn[csr_s[j]*5+k]);
            a2[h*8+k] = a;
        }
        __syncthreads();
        if (tl < 120){
            int c8 = tl*8;
            float a[5];
            #pragma unroll
            for (int k=0;k<5;k++) a[k] = a2[h*8+k];
            float r[8];
            short8 bb = *(const short8*)(b1 + c8);
            #pragma unroll
            for (int j=0;j<8;j++) r[j] = bf2f(((u16*)&bb)[j]);
            #pragma unroll
            for (int k=0;k<5;k++){
                short8 wv = *(const short8*)(W1 + k*HID + c8);
                #pragma unroll
                for (int j=0;j<8;j++) r[j] += a[k]*bf2f(((u16*)&wv)[j]);
            }
            short8 o;
            #pragma unroll
            for (int j=0;j<8;j++) ((u16*)&o)[j] = f2bf(fmaxf(r[j],0.f));
            *(short8*)(h1b + (size_t)n*HID + c8) = o;
        }
    } else {
        int bb = b - 8192;
        int z = bb/240, r = bb%240;
        if (z==0)      vecmat_body(r%15, r/15, b2f,    projWn,            tvb,  smem);
        else if (z==1) vecmat_body(r%15, r/15, projbf, fuseWn + 640*HID,  cC,   smem);
        else           vecmat_body(r%15, r/15, b2f,    fuseWn + 1600*HID, gvec, smem);
    }
}
// L5: p1 (4096) + vecmat vb (240) + addc c0 (4)
__global__ __launch_bounds__(256) void k_L5(const u16* __restrict__ h1b, const float* __restrict__ dinv,
                                            const int* __restrict__ off, const int* __restrict__ csr_s,
                                            const float* __restrict__ csr_w, u16* __restrict__ P1b,
                                            const float* tvb, const u16* fuseWn, float* vb,
                                            const float* cC, const float* gvec, const u16* fusebn, float* c0){
    __shared__ __attribute__((aligned(16))) char smem[1024];
    int b = blockIdx.x;
    if (b < 4096){
        int wv = threadIdx.x>>6, lane = threadIdx.x&63;
        int n = b*4 + wv;
        int c = lane*16;
        bool act = lane < 60;
        float di = dinv[n], sw = di*di;
        float acc[16];
        if (act){
            short8 h0 = *(const short8*)(h1b + (size_t)n*HID + c);
            short8 h1v = *(const short8*)(h1b + (size_t)n*HID + c + 8);
            #pragma unroll
            for (int j=0;j<8;j++){ acc[j] = sw*bf2f(((u16*)&h0)[j]); acc[8+j] = sw*bf2f(((u16*)&h1v)[j]); }
        } else {
            #pragma unroll
            for (int j=0;j<16;j++) acc[j] = 0.f;
        }
        int j0 = off[n], j1 = off[n+1];
        for (int j=j0;j<j1;j++){
            int s = csr_s[j]; float w = csr_w[j];
            if (act){
                short8 v0 = *(const short8*)(h1b + (size_t)s*HID + c);
                short8 v1 = *(const short8*)(h1b + (size_t)s*HID + c + 8);
                #pragma unroll
                for (int j2=0;j2<8;j2++){ acc[j2] += w*bf2f(((u16*)&v0)[j2]); acc[8+j2] += w*bf2f(((u16*)&v1)[j2]); }
            }
        }
        if (act){
            short8 o0, o1;
            #pragma unroll
            for (int j=0;j<8;j++){ ((u16*)&o0)[j] = f2bf(acc[j]); ((u16*)&o1)[j] = f2bf(acc[8+j]); }
            *(short8*)(P1b + (size_t)n*HID + c) = o0;
            *(short8*)(P1b + (size_t)n*HID + c + 8) = o1;
        }
    } else if (b < 4336){
        int bb = b - 4096;
        vecmat_body(bb%15, bb/15, tvb, fuseWn + 640*HID, vb, smem);
    } else {
        int c = (b-4336)*256 + threadIdx.x;
        if (c < HID) c0[c] = cC[c] + gvec[c] + bf2f(fusebn[c]);
    }
}
// L6: pr (2048) + gm (120)
__global__ __launch_bounds__(256) void k_L6(const u16* __restrict__ P1b, const int* __restrict__ fgi,
                                            const int* __restrict__ ptr, u16* __restrict__ prb,
                                            float* __restrict__ evec, u16* __restrict__ maskb,
                                            float* __restrict__ maskf, const int* __restrict__ flag,
                                            u16* __restrict__ gmb){
    int b = blockIdx.x;
    if (b < 2048){
        int wv = threadIdx.x>>6, lane = threadIdx.x&63;
        int bf = b*4 + wv;
        int mb = bf >> 5;
        int base = ptr[mb];
        int c = lane*16;
        bool act = lane < 60;
        float acc[16];
        #pragma unroll
        for (int j=0;j<16;j++) acc[j] = 0.f;
        int cnt = 0;
        #pragma unroll
        for (int a=0;a<AMAXA;a++){
            int idx = fgi[bf*AMAXA + a];
            if (idx >= 0){
                cnt++;
                if (act){
                    short8 v0 = *(const short8*)(P1b + (size_t)(base+idx)*HID + c);
                    short8 v1 = *(const short8*)(P1b + (size_t)(base+idx)*HID + c + 8);
                    #pragma unroll
                    for (int j=0;j<8;j++){ acc[j] += bf2f(((u16*)&v0)[j]); acc[8+j] += bf2f(((u16*)&v1)[j]); }
                }
            }
        }
        float inv = (cnt>0) ? 1.0f/(float)cnt : 0.0f;
        if (act){
            short8 o0, o1;
            #pragma unroll
            for (int j=0;j<8;j++){ ((u16*)&o0)[j] = f2bf(acc[j]*inv); ((u16*)&o1)[j] = f2bf(acc[8+j]*inv); }
            *(short8*)(prb + swzA(bf, c)) = o0;
            *(short8*)(prb + swzA(bf, c+8)) = o1;
        }
        if (lane == 0){
            float e = (cnt>0) ? 1.0f : 0.0f;
            evec[bf] = e;
            if (*flag) maskf[bf] = e;
            else       maskb[bf] = f2bf(e);
        }
    } else {
        int id = (b-2048)*256 + threadIdx.x;   // 256 mol * 120 c8
        int mb = id / 120; int c8 = (id - mb*120)*8;
        float s[8] = {0,0,0,0,0,0,0,0};
        for (int i=0;i<NPM;i++){
            short8 v = *(const short8*)(P1b + (size_t)(mb*NPM+i)*HID + c8);
            #pragma unroll
            for (int j=0;j<8;j++) s[j] += bf2f(((u16*)&v)[j]);
        }
        const float inv = 1.0f/(float)NPM;
        short8 o;
        #pragma unroll
        for (int j=0;j<8;j++) ((u16*)&o)[j] = f2bf(s[j]*inv);
        *(short8*)(gmb + (size_t)mb*HID + c8) = o;
    }
}
// L7: Gc = gm @ WglobT^T + c0
__global__ __launch_bounds__(256) void k_L7(const u16* gmb, const u16* WglobT, float* Gc, const float* c0){
    __shared__ __attribute__((aligned(16))) char smem[10240];
    int b = blockIdx.x;
    gemm64f(b%4, b/4, gmb, HID, WglobT, HID, Gc, B_MOL, HID, c0, smem);
}

// L8 final GEMM: out[8192,960] = prb @ WbigS^T + epilogue
// BM=128, BN=96, BK=32, dbuf swizzled staging; grid 64x10=640
__global__ __launch_bounds__(256) void k_gemmF(
    const u16* __restrict__ A, const u16* __restrict__ Bt,
    float* __restrict__ Cf, u16* __restrict__ Cb,
    const int* __restrict__ fg_type, const float* __restrict__ evec,
    const float* __restrict__ fgA, const float* __restrict__ pWbM,
    const float* __restrict__ vb, const float* __restrict__ Gc,
    const int* __restrict__ flag)
{
    __shared__ __attribute__((aligned(16))) u16 S[2][14*512];   // A regions 0..7, B regions 8..13
    const int tid = threadIdx.x;
    const int wave = tid>>6, lane = tid&63;
    const int wm = wave>>1, wn = wave&1;
    const int q = lane>>4, l16 = lane&15;
    const int m0 = blockIdx.x*128, n0 = blockIdx.y*96;
    const int R0 = blockIdx.x*8, N0 = blockIdx.y*6;

    f32x4 acc[4][3];
    #pragma unroll
    for (int i=0;i<4;i++)
        #pragma unroll
        for (int j=0;j<3;j++) acc[i][j] = (f32x4){0,0,0,0};

    const u16* gA0 = A  + ((size_t)(R0 + wave*2    )*30)*512 + lane*8;
    const u16* gA1 = A  + ((size_t)(R0 + wave*2 + 1)*30)*512 + lane*8;
    const u16* gB0 = Bt + ((size_t)(N0 + wave      )*30)*512 + lane*8;
    const u16* gB1 = Bt + ((size_t)(N0 + 4 + wave  )*30)*512 + lane*8;  // only wave<2

    gload_lds16(gA0, &S[0][(wave*2  )*512]);
    gload_lds16(gA1, &S[0][(wave*2+1)*512]);
    gload_lds16(gB0, &S[0][(8+wave)*512]);
    if (wave < 2) gload_lds16(gB1, &S[0][(12+wave)*512]);

    int buf = 0;
    for (int kc=0; kc<30; kc++){
        __syncthreads();
        if (kc < 29){
            int kn = (kc+1)*512;
            gload_lds16(gA0 + kn, &S[buf^1][(wave*2  )*512]);
            gload_lds16(gA1 + kn, &S[buf^1][(wave*2+1)*512]);
            gload_lds16(gB0 + kn, &S[buf^1][(8+wave)*512]);
            if (wave < 2) gload_lds16(gB1 + kn, &S[buf^1][(12+wave)*512]);
        }
        short8 af[4], bfr[3];
        #pragma unroll
        for (int i=0;i<4;i++) af[i] = *(const short8*)(&S[buf][(wm*4+i)*512 + lane*8]);
        #pragma unroll
        for (int j=0;j<3;j++) bfr[j] = *(const short8*)(&S[buf][(8+wn*3+j)*512 + lane*8]);
        #pragma unroll
        for (int i=0;i<4;i++)
            #pragma unroll
            for (int j=0;j<3;j++)
                acc[i][j] = __builtin_amdgcn_mfma_f32_16x16x32_bf16(af[i], bfr[j], acc[i][j], 0,0,0);
        buf ^= 1;
    }

    const int isf = *flag;
    #pragma unroll
    for (int i=0;i<4;i++){
        int rowb = m0 + wm*64 + i*16 + q*4;
        #pragma unroll
        for (int r=0;r<4;r++){
            int row = rowb + r;
            int bb = row>>5, ff = row&31;
            int ty = fg_type[row];
            float e = evec[row];
            #pragma unroll
            for (int j=0;j<3;j++){
                int col = n0 + wn*48 + j*16 + l16;
                float v = acc[i][j][r]
                        + fgA[ty*HID+col] + pWbM[ff*HID+col]
                        + e*vb[col] + Gc[bb*HID+col];
                if (isf) Cf[(size_t)row*HID + col] = v;
                else     Cb[(size_t)row*HID + col] = f2bf(v);
            }
        }
    }
}

extern "C" void kernel_launch(void* const* d_in, const int* in_sizes, int n_in,
                              void* d_out, int out_size, void* d_ws, size_t ws_size,
                              hipStream_t stream) {
    const int* edge_idx  = (const int*)d_in[1];
    const int* ptr       = (const int*)d_in[3];
    const int* fg_type   = (const int*)d_in[4];
    const int* fg_idx    = (const int*)d_in[5];

    // ---- workspace layout ----
    char* w = (char*)d_ws;
    auto nxt = [&](size_t b)->char*{ char* p = w; w += (b + 255) & ~(size_t)255; return p; };
    u16* big0   = (u16*)nxt((size_t)N_NODES*HID*2);       // fuseWT+Ub -> h1b -> prb(swizzled)
    u16* fuseWT = big0;
    u16* Ub     = big0 + (size_t)HID*2560;
    u16* h1b    = big0;
    u16* prb    = big0;
    u16* P1b    = (u16*)nxt((size_t)N_NODES*HID*2);
    u16*  WbigS  = (u16*) nxt((size_t)HID*HID*2);
    u16*  WglobT = (u16*) nxt((size_t)HID*HID*2);
    float* fgA   = (float*)nxt((size_t)NFG*HID*4);
    float* pWbM  = (float*)nxt((size_t)FMAXF*HID*4);
    float* b2f   = (float*)nxt(HID*4);
    float* projbf= (float*)nxt(HID*4);
    float* tvb   = (float*)nxt(HID*4);   // tvb, vb? keep tvb,cC,gvec contiguous zero-block of 4*HID
    float* cC    = (float*)nxt(HID*4);
    float* gvec  = (float*)nxt(HID*4);
    float* vb    = (float*)nxt(HID*4);   // vb zeroed too (part of z4? no) -> zero via 4*HID block: tvb,cC,gvec,vb
    float* c0    = (float*)nxt(HID*4);
    int*   deg   = (int*)  nxt(N_NODES*4);
    float* dinv  = (float*)nxt(N_NODES*4);
    int*   off   = (int*)  nxt((N_NODES+1)*4);
    int*   cur   = (int*)  nxt(N_NODES*4);
    int*   csr_s = (int*)  nxt(E_EDGES*4);
    float* csr_w = (float*)nxt(E_EDGES*4);
    float* evec  = (float*)nxt(BF_ROWS*4);
    u16*   gmb   = (u16*)  nxt((size_t)B_MOL*HID*2);
    float* Gc    = (float*)nxt((size_t)B_MOL*HID*4);
    int*   flag  = (int*)  nxt(256);
    u16*   region= (u16*)  nxt((size_t)NTOT*2);
    // views into region
    u16* gxn    = region;
    u16* W1n    = region +   81920;
    u16* b1n    = region +   86720;
    u16* W2n    = region +   87680;
    u16* fgeN   = region + 1010240;
    u16* posN   = region + 1115200;
    u16* projWn = region + 1135680;
    u16* fuseWn = region + 2058240;
    u16* fusebn = region + 4515840;

    NormSrcs ns;
    ns.p[0]=d_in[0]; ns.p[1]=d_in[6]; ns.p[2]=d_in[7]; ns.p[3]=d_in[8]; ns.p[4]=d_in[9];
    ns.p[5]=d_in[10]; ns.p[6]=d_in[11]; ns.p[7]=d_in[12]; ns.p[8]=d_in[13]; ns.p[9]=d_in[14]; ns.p[10]=d_in[15];
    // L0: normalize (+flag, +b2f/projbf, zero deg and tvb..vb [4*HID contiguous])
    k_normAll<<<(NTOT+255)/256,256,0,stream>>>(ns, region, b2f, projbf, tvb, flag, deg);
    // L1: transpose fuseW + hist
    k_L1<<<2656,256,0,stream>>>(fuseWn, fuseWT, edge_idx + E_EDGES, deg);
    // L2: Ub, WglobT + scan/dinv
    k_L2<<<451,256,0,stream>>>(fuseWT, projWn, W2n, Ub, WglobT, deg, off, cur, dinv);
    // L3: WbigS(swz) + fgA/pWbM + scatter
    k_L3<<<556,256,0,stream>>>(Ub, W2n, WbigS, fgeN, posN, fuseWT, fgA, pWbM,
                               edge_idx, edge_idx + E_EDGES, dinv, cur, csr_s, csr_w);
    // L4: aggx+h1 fused + vecmat3 (tvb,cC,gvec)
    k_L4<<<8912,256,0,stream>>>(gxn, dinv, off, csr_s, csr_w, W1n, b1n, h1b,
                                b2f, projbf, fuseWn, projWn, tvb, cC, gvec);
    // L5: p1 + vecmat(vb) + addc(c0)
    k_L5<<<4340,256,0,stream>>>(h1b, dinv, off, csr_s, csr_w, P1b,
                                tvb, fuseWn, vb, cC, gvec, fusebn, c0);
    // L6: pr (swizzled prb + mask) + gm
    k_L6<<<2168,256,0,stream>>>(P1b, fg_idx, ptr, prb, evec,
                                (u16*)d_out + OUT1, (float*)d_out + OUT1, flag, gmb);
    // L7: Gc = gm @ (W2 Wd) + c0
    k_L7<<<60,256,0,stream>>>(gmb, WglobT, Gc, c0);
    // L8: final GEMM + epilogue
    k_gemmF<<<dim3(64,10),256,0,stream>>>(prb, WbigS, (float*)d_out, (u16*)d_out,
                                          fg_type, evec, fgA, pWbM, vb, Gc, flag);
    (void)in_sizes; (void)n_in; (void)out_size; (void)ws_size;
}